// Round 13
// baseline (221.364 us; speedup 1.0000x reference)
//
#include <hip/hip_runtime.h>
#include <hip/hip_bf16.h>
#include <cmath>

#define NB 4
#define NS 1024
#define ND 1024
#define NH 16
#define NDH 64
#define NKSP 32
#define SCALE 0.125f      // 1/sqrt(64)
#define LOG2E 1.44269504f
#define SCALE2 (SCALE * LOG2E)

typedef __attribute__((ext_vector_type(8))) short bf16x8;
typedef __attribute__((ext_vector_type(4))) float f32x4;
typedef unsigned long long u64;

#define AS1 __attribute__((address_space(1)))
#define AS3 __attribute__((address_space(3)))

__device__ __forceinline__ void gl_lds16(const void* g, void* l) {
    __builtin_amdgcn_global_load_lds((const AS1 void*)g, (AS3 void*)l, 16, 0, 0);
}

__device__ __forceinline__ ushort f2bf(float f) {
    union { __hip_bfloat16 h; ushort u; } cv;
    cv.h = __float2bfloat16(f);
    return cv.u;
}
__device__ __forceinline__ float bf2f(ushort u) {
    union { unsigned int i; float f; } cv;
    cv.i = ((unsigned int)u) << 16;
    return cv.f;
}
__device__ __forceinline__ float fexp2(float x) {
    return __builtin_amdgcn_exp2f(x);   // v_exp_f32 (base-2)
}

// ---------------------------------------------------------------------------
// y=0: x->bf16 (4096 blocks); y=1..4: W->bf16 (1024 blocks);
// y=5: pack pmask into bitwords (4096 blocks, one wave per u64 word).
// ---------------------------------------------------------------------------
__global__ __launch_bounds__(256)
void f2bf_multi(const float* __restrict__ x,
                const float* __restrict__ w0, const float* __restrict__ w1,
                const float* __restrict__ w2, const float* __restrict__ w3,
                const int* __restrict__ pm,
                ushort* __restrict__ xo,
                ushort* __restrict__ o0, ushort* __restrict__ o1,
                ushort* __restrict__ o2, ushort* __restrict__ o3,
                u64* __restrict__ bm)
{
    int y = blockIdx.y;
    if (y == 5) {
        int word = blockIdx.x * 4 + (threadIdx.x >> 6);
        int lane = threadIdx.x & 63;
        int row  = word >> 4, wcol = word & 15;
        int v = pm[(size_t)row * NS + wcol * 64 + lane];
        u64 b = __ballot(v != 0);
        if (lane == 0) bm[word] = b;
        return;
    }
    const float* src; ushort* dst; int nblk;
    if (y == 0)      { src = x;  dst = xo; nblk = 4096; }
    else if (y == 1) { src = w0; dst = o0; nblk = 1024; }
    else if (y == 2) { src = w1; dst = o1; nblk = 1024; }
    else if (y == 3) { src = w2; dst = o2; nblk = 1024; }
    else             { src = w3; dst = o3; nblk = 1024; }
    if (blockIdx.x >= (unsigned)nblk) return;
    int i = (blockIdx.x * 256 + threadIdx.x) * 4;
    float4 v = *(const float4*)&src[i];
    ushort4 o;
    o.x = f2bf(v.x); o.y = f2bf(v.y); o.z = f2bf(v.z); o.w = f2bf(v.w);
    *(ushort4*)&dst[i] = o;
}

// ---------------------------------------------------------------------------
// Fused QKV GEMM. grid (24,32): blockIdx.x: [0,8)=Q [8,16)=K [16,24)=V.
// LDS chunk swizzle sigma(c) = c ^ ((c>>3)&7): swizzled global SOURCE +
// linear LDS dest + swizzled fragment read (rule #21).
// ---------------------------------------------------------------------------
__global__ __launch_bounds__(256)
void gemm_qkv(const ushort* __restrict__ xb,
              const ushort* __restrict__ Wqb, const ushort* __restrict__ Wkb,
              const ushort* __restrict__ Wvb,
              const float* __restrict__ bq, const float* __restrict__ bk,
              const float* __restrict__ bv,
              ushort* __restrict__ Qo, ushort* __restrict__ Ko,
              ushort* __restrict__ Vo)
{
    constexpr int K = ND;
    __shared__ __attribute__((aligned(16))) ushort As[128 * 32];
    __shared__ __attribute__((aligned(16))) ushort Bs[128 * 32];

    const int tid  = threadIdx.x;
    const int lane = tid & 63, w = tid >> 6;
    const int wm = w >> 1, wn = w & 1;
    const int which = blockIdx.x >> 3;
    const int n0 = (blockIdx.x & 7) * 128;
    const int m0 = blockIdx.y * 128;
    const int quad = lane >> 4, l16 = lane & 15;

    const ushort* W = (which == 0) ? Wqb : (which == 1) ? Wkb : Wvb;
    const float* bias = (which == 0) ? bq : (which == 1) ? bk : bv;
    ushort* Out = (which == 0) ? Qo : (which == 1) ? Ko : Vo;

    f32x4 acc[4][4] = {};

    for (int k0 = 0; k0 < K; k0 += 32) {
        __syncthreads();
#pragma unroll
        for (int u = 0; u < 2; ++u) {
            int t0 = u * 256 + w * 64;
            int t  = t0 + lane;
            int c  = t ^ ((t >> 3) & 7);          // source swizzle
            int row = c >> 2, kc = (c & 3) * 8;
            gl_lds16(xb + (size_t)(m0 + row) * K + k0 + kc, &As[t0 * 8]);
            gl_lds16(W  + (size_t)(n0 + row) * K + k0 + kc, &Bs[t0 * 8]);
        }
        __syncthreads();

        bf16x8 af[4], bfr[4];
#pragma unroll
        for (int mt = 0; mt < 4; ++mt) {
            int cidx = (wm*64 + mt*16 + l16)*4 + quad;
            int p = cidx ^ ((cidx >> 3) & 7);     // swizzled read
            af[mt] = *(const bf16x8*)&As[p * 8];
        }
#pragma unroll
        for (int nt = 0; nt < 4; ++nt) {
            int cidx = (wn*64 + nt*16 + l16)*4 + quad;
            int p = cidx ^ ((cidx >> 3) & 7);
            bfr[nt] = *(const bf16x8*)&Bs[p * 8];
        }
#pragma unroll
        for (int mt = 0; mt < 4; ++mt)
#pragma unroll
            for (int nt = 0; nt < 4; ++nt)
                acc[mt][nt] = __builtin_amdgcn_mfma_f32_16x16x32_bf16(
                    af[mt], bfr[nt], acc[mt][nt], 0, 0, 0);
    }

#pragma unroll
    for (int nt = 0; nt < 4; ++nt) {
        int n = n0 + wn*64 + nt*16 + l16;
        float bz = bias[n];
        int hh = n >> 6, dh = n & 63;
#pragma unroll
        for (int mt = 0; mt < 4; ++mt) {
#pragma unroll
            for (int rg = 0; rg < 4; ++rg) {
                int m = m0 + wm*64 + mt*16 + quad*4 + rg;
                int b = m >> 10, s = m & (NS - 1);
                Out[(((size_t)(b*NH + hh))*NS + s)*NDH + dh] =
                    f2bf(acc[mt][nt][rg] + bz);
            }
        }
    }
}

// ---------------------------------------------------------------------------
// V transpose: [b,h,s,dh] -> [b,h,dh,s], 64x64 tiles, XOR-swizzled LDS,
// coalesced 16B global on both sides. 1024 blocks x 256 thr, 8KB LDS.
// ---------------------------------------------------------------------------
__global__ __launch_bounds__(256)
void transpose_v(const ushort* __restrict__ V, ushort* __restrict__ Vt)
{
    __shared__ __attribute__((aligned(16))) ushort T[64 * 64];

    const int t  = threadIdx.x;
    const int bh = blockIdx.x >> 4;               // 0..63 (b*16+h)
    const int st = blockIdx.x & 15;               // s-tile
    const ushort* Vh  = V  + (size_t)bh * NS * NDH + (size_t)st * 64 * NDH;
    ushort*       Vth = Vt + (size_t)bh * NDH * NS + st * 64;

#pragma unroll
    for (int i = 0; i < 2; ++i) {
        int g = i * 256 + t;                      // 0..511
        int srow = g >> 3, sub = g & 7;
        union { bf16x8 v; ushort u[8]; } x;
        x.v = *(const bf16x8*)&Vh[(size_t)srow * NDH + sub * 8];
#pragma unroll
        for (int e = 0; e < 8; ++e) {
            int dh = sub * 8 + e;                 // dh>>3 == sub
            T[dh*64 + (((srow >> 3) ^ sub) * 8) + (srow & 7)] = x.u[e];
        }
    }
    __syncthreads();
#pragma unroll
    for (int i = 0; i < 2; ++i) {
        int g = i * 256 + t;
        int dh = g >> 3, sc = g & 7;
        bf16x8 v = *(const bf16x8*)&T[dh*64 + ((sc ^ (dh >> 3)) * 8)];
        *(bf16x8*)&Vth[(size_t)dh * NS + sc * 8] = v;
    }
}

// ---------------------------------------------------------------------------
// Output GEMM: 64x128 tile -> 512 blocks. Same chunk swizzle as gemm_qkv.
// ---------------------------------------------------------------------------
__global__ __launch_bounds__(256)
void gemm_out(const ushort* __restrict__ A, const ushort* __restrict__ W,
              const float* __restrict__ bias, float* __restrict__ Cout)
{
    constexpr int K = ND;
    __shared__ __attribute__((aligned(16))) ushort As[64 * 32];
    __shared__ __attribute__((aligned(16))) ushort Bs[128 * 32];

    const int tid  = threadIdx.x;
    const int lane = tid & 63, w = tid >> 6;
    const int wm = w & 1, wn = w >> 1;
    const int m0 = blockIdx.y * 64, n0 = blockIdx.x * 128;
    const int quad = lane >> 4, l16 = lane & 15;

    f32x4 acc[2][4] = {};

    for (int k0 = 0; k0 < K; k0 += 32) {
        __syncthreads();
        {
            int t0 = w * 64;
            int t  = t0 + lane;
            int c  = t ^ ((t >> 3) & 7);
            int row = c >> 2, kc = (c & 3) * 8;
            gl_lds16(A + (size_t)(m0 + row) * K + k0 + kc, &As[t0 * 8]);
        }
#pragma unroll
        for (int u = 0; u < 2; ++u) {
            int t0 = u * 256 + w * 64;
            int t  = t0 + lane;
            int c  = t ^ ((t >> 3) & 7);
            int row = c >> 2, kc = (c & 3) * 8;
            gl_lds16(W + (size_t)(n0 + row) * K + k0 + kc, &Bs[t0 * 8]);
        }
        __syncthreads();

        bf16x8 af[2], bfr[4];
#pragma unroll
        for (int mt = 0; mt < 2; ++mt) {
            int cidx = (wm*32 + mt*16 + l16)*4 + quad;
            int p = cidx ^ ((cidx >> 3) & 7);
            af[mt] = *(const bf16x8*)&As[p * 8];
        }
#pragma unroll
        for (int nt = 0; nt < 4; ++nt) {
            int cidx = (wn*64 + nt*16 + l16)*4 + quad;
            int p = cidx ^ ((cidx >> 3) & 7);
            bfr[nt] = *(const bf16x8*)&Bs[p * 8];
        }
#pragma unroll
        for (int mt = 0; mt < 2; ++mt)
#pragma unroll
            for (int nt = 0; nt < 4; ++nt)
                acc[mt][nt] = __builtin_amdgcn_mfma_f32_16x16x32_bf16(
                    af[mt], bfr[nt], acc[mt][nt], 0, 0, 0);
    }

#pragma unroll
    for (int nt = 0; nt < 4; ++nt) {
        int n = n0 + wn*64 + nt*16 + l16;
        float bz = bias[n];
#pragma unroll
        for (int mt = 0; mt < 2; ++mt) {
#pragma unroll
            for (int rg = 0; rg < 4; ++rg) {
                int m = m0 + wm*32 + mt*16 + quad*4 + rg;
                Cout[(size_t)m * ND + n] = acc[mt][nt][rg] + bz;
            }
        }
    }
}

// ---------------------------------------------------------------------------
// Round 13: attn_fused = dense + sparse in ONE dispatch (single-stream
// overlap; sparse fills CUs idle under dense). Enabler: dense LDS shrunk
// 51.2KB -> 18.4KB so sparse co-residency isn't taxed:
//  - K fragments DIRECT from global (r0-r4 measured LDS-staged == direct
//    three times; drops KK 32KB AND all staging barriers — dense K-loop
//    now has ZERO barriers).
//  - wk-partial combine through ONE 10.2KB slot in 3 barriered rounds,
//    aliased onto dead Ps.
// Grid 4096: ids [0,nd*512) dense (longest first), then ns*1024 sparse,
// surplus exits. Per-block path uniform -> barrier-safe divergence.
// ---------------------------------------------------------------------------
#define FLOADKV(KF, VF, KT)                                                   \
    _Pragma("unroll")                                                         \
    for (int nt = 0; nt < 4; ++nt)                                            \
        _Pragma("unroll")                                                     \
        for (int kk = 0; kk < 2; ++kk) {                                      \
            KF[nt][kk] = *(const bf16x8*)                                     \
                &Kh[(size_t)((KT)*64 + nt*16 + l16) * NDH + kk*32 + quad*8];  \
            VF[nt][kk] = *(const bf16x8*)                                     \
                &Vth[(size_t)(nt*16 + l16) * NS + (KT)*64 + kk*32 + quad*8];  \
        }

#define DSTEP(KF, VF, M0, M1)                                                 \
    _Pragma("unroll")                                                         \
    for (int qh = 0; qh < 2; ++qh) {                                          \
        const int qrow = qh*16 + l16;                                         \
        u64 wqm = ((qh == 0) ? (M0) : (M1)) >> (quad * 4);                    \
        f32x4 s_acc[4] = {};                                                  \
        __builtin_amdgcn_s_setprio(1);                                        \
        _Pragma("unroll")                                                     \
        for (int nt = 0; nt < 4; ++nt)                                        \
            _Pragma("unroll")                                                 \
            for (int kk = 0; kk < 2; ++kk)                                    \
                s_acc[nt] = __builtin_amdgcn_mfma_f32_16x16x32_bf16(          \
                    KF[nt][kk], qf[qh][kk], s_acc[nt], 0, 0, 0);              \
        __builtin_amdgcn_s_setprio(0);                                        \
        _Pragma("unroll")                                                     \
        for (int nt = 0; nt < 4; ++nt) {                                      \
            ushort4 pk;                                                       \
            float p0 = fexp2(fmaf(s_acc[nt][0], SCALE2,                       \
                 ((wqm >> (nt*16 + 0)) & 1ULL) ? 0.f : nlam2));               \
            float p1 = fexp2(fmaf(s_acc[nt][1], SCALE2,                       \
                 ((wqm >> (nt*16 + 1)) & 1ULL) ? 0.f : nlam2));               \
            float p2 = fexp2(fmaf(s_acc[nt][2], SCALE2,                       \
                 ((wqm >> (nt*16 + 2)) & 1ULL) ? 0.f : nlam2));               \
            float p3 = fexp2(fmaf(s_acc[nt][3], SCALE2,                       \
                 ((wqm >> (nt*16 + 3)) & 1ULL) ? 0.f : nlam2));               \
            pk.x = f2bf(p0); pk.y = f2bf(p1);                                 \
            pk.z = f2bf(p2); pk.w = f2bf(p3);                                 \
            *(ushort4*)&Ps[w*2304 + qrow*72 + nt*16 + quad*4] = pk;           \
        }                                                                     \
        bf16x8 pf[2];                                                         \
        _Pragma("unroll")                                                     \
        for (int kk = 0; kk < 2; ++kk)                                        \
            pf[kk] = *(const bf16x8*)&Ps[w*2304 + qrow*72 + kk*32 + quad*8];  \
        __builtin_amdgcn_s_setprio(1);                                        \
        _Pragma("unroll")                                                     \
        for (int kk = 0; kk < 2; ++kk) {                                      \
            l_acc[qh] = __builtin_amdgcn_mfma_f32_16x16x32_bf16(              \
                pf[kk], ones.v, l_acc[qh], 0, 0, 0);                          \
            _Pragma("unroll")                                                 \
            for (int nt = 0; nt < 4; ++nt)                                    \
                o_acc[qh][nt] = __builtin_amdgcn_mfma_f32_16x16x32_bf16(      \
                    pf[kk], VF[nt][kk], o_acc[qh][nt], 0, 0, 0);              \
        }                                                                     \
        __builtin_amdgcn_s_setprio(0);                                        \
    }

__global__ __launch_bounds__(256)
void attn_fused(const ushort* __restrict__ Qb, const ushort* __restrict__ Kb,
                const ushort* __restrict__ Vb, const ushort* __restrict__ Vt,
                const u64* __restrict__ bm,
                const int* __restrict__ pidx, const int* __restrict__ pimask,
                const float* __restrict__ u_prev, ushort* __restrict__ OA)
{
    // Ps: 4 waves x 2304 ushorts = 18432 B. POUT (2560 floats = 10240 B)
    // aliases Ps after the dense K-loop. Sparse path uses no LDS.
    __shared__ __attribute__((aligned(16))) ushort SM[9216];
    ushort* Ps = SM;

    const int tid  = threadIdx.x;
    const int lane = tid & 63, w = tid >> 6;      // 4 waves
    const int quad = lane >> 4, l16 = lane & 15;

    // classify batches (uniform across blocks: same u_prev math)
    float lams[4];
#pragma unroll
    for (int i = 0; i < 4; ++i) lams[i] = 10.0f * __expf(-5.0f * u_prev[i]);
    int dl[4], sl[4], nd = 0, ns = 0;
#pragma unroll
    for (int i = 0; i < 4; ++i) if (lams[i] <  1.0f) dl[nd++] = i;
#pragma unroll
    for (int i = 0; i < 4; ++i) if (lams[i] >= 1.0f) sl[ns++] = i;

    const int id = blockIdx.x;                    // grid 4096

    if (id < nd * 512) {
        // ======================= DENSE path ==============================
        int xcd = id & 7, j = id >> 3;            // j in [0, nd*64)
        int nh2 = 2 * nd;
        int hi = j % nh2, qt = j / nh2;           // qt in [0,32)
        int gh = hi * 8 + xcd;
        const int b = dl[gh >> 4], h = gh & 15;
        const int s0 = qt * 32;
        const float nlam2 = -lams[b] * LOG2E;

        const size_t bh = (size_t)b * NH + h;
        const ushort* Qh  = Qb + bh * NS * NDH;
        const ushort* Kh  = Kb + bh * NS * NDH;
        const ushort* Vth = Vt + bh * NDH * NS;

        bf16x8 qf[2][2];
#pragma unroll
        for (int qh = 0; qh < 2; ++qh)
#pragma unroll
            for (int kk = 0; kk < 2; ++kk)
                qf[qh][kk] = *(const bf16x8*)
                    &Qh[(size_t)(s0 + qh*16 + l16) * NDH + kk*32 + quad*8];

        union { bf16x8 v; ushort s[8]; } ones;
#pragma unroll
        for (int i = 0; i < 8; ++i) ones.s[i] = 0x3F80;  // bf16 1.0

        f32x4 o_acc[2][4] = {};
        f32x4 l_acc[2] = {};

        // K-loop: ZERO barriers (per-wave Ps, direct-global K/V)
        for (int t = 0; t < 4; ++t) {
            const int kt = 4 * t + w;             // this wave's kt slot
            u64 m0 = bm[(size_t)(s0 +  0 + l16) * 16 + kt];
            u64 m1 = bm[(size_t)(s0 + 16 + l16) * 16 + kt];
            bf16x8 kf[4][2], vf[4][2];
            FLOADKV(kf, vf, kt);
            DSTEP(kf, vf, m0, m1);
        }
        __syncthreads();                          // Ps dead -> POUT

        // combine the 3 partial waves through ONE 2560-float slot
        float* POUT = (float*)SM;
        for (int s = 1; s <= 3; ++s) {
            if (w == s) {
#pragma unroll
                for (int qh = 0; qh < 2; ++qh) {
#pragma unroll
                    for (int nt = 0; nt < 4; ++nt)
#pragma unroll
                        for (int rg = 0; rg < 4; ++rg)
                            POUT[(qh*16 + nt*4 + rg)*64 + lane] =
                                o_acc[qh][nt][rg];
#pragma unroll
                    for (int rg = 0; rg < 4; ++rg)
                        POUT[(32 + qh*4 + rg)*64 + lane] = l_acc[qh][rg];
                }
            }
            __syncthreads();
            if (w == 0) {
#pragma unroll
                for (int qh = 0; qh < 2; ++qh) {
#pragma unroll
                    for (int nt = 0; nt < 4; ++nt)
#pragma unroll
                        for (int rg = 0; rg < 4; ++rg)
                            o_acc[qh][nt][rg] +=
                                POUT[(qh*16 + nt*4 + rg)*64 + lane];
#pragma unroll
                    for (int rg = 0; rg < 4; ++rg)
                        l_acc[qh][rg] += POUT[(32 + qh*4 + rg)*64 + lane];
                }
            }
            __syncthreads();
        }

        if (w == 0) {
            // epilogue (row = qh*16 + quad*4 + rg, col = dh nt*16 + l16)
#pragma unroll
            for (int qh = 0; qh < 2; ++qh) {
                float inv[4];
#pragma unroll
                for (int rg = 0; rg < 4; ++rg) inv[rg] = 1.f / l_acc[qh][rg];
#pragma unroll
                for (int nt = 0; nt < 4; ++nt)
#pragma unroll
                    for (int rg = 0; rg < 4; ++rg) {
                        int m = qh*16 + quad*4 + rg;
                        OA[((size_t)b*NS + s0 + m)*ND + h*NDH + nt*16 + l16] =
                            f2bf(o_acc[qh][nt][rg] * inv[rg]);
                    }
            }
        }
    } else {
        // ======================= SPARSE path =============================
        const int sid = id - nd * 512;
        if (sid >= ns * 1024) return;             // surplus blocks exit

        const int kj = lane >> 3;                 // key slot 0..7
        const int c  = lane & 7;                  // 16B chunk 0..7

        int xcd = sid & 7, j = sid >> 3;
        int nh2 = 2 * ns;
        int hi = j % nh2, qt = j / nh2;           // qt in [0,64)
        int gh = hi * 8 + xcd;
        const int b = sl[gh >> 4], h = gh & 15;
        const int s0 = qt * 16 + w * 4;

        const size_t bh = (size_t)b * NH + h;
        const ushort* Qh = Qb + bh * NS * NDH;
        const ushort* Kh = Kb + bh * NS * NDH;
        const ushort* Vh = Vb + bh * NS * NDH;

        for (int r = 0; r < 4; ++r) {
            const int s = s0 + r;

            float qf[8];
            {
                union { bf16x8 v; ushort u[8]; } qv;
                qv.v = *(const bf16x8*)&Qh[(size_t)s * NDH + c * 8];
#pragma unroll
                for (int e = 0; e < 8; ++e) qf[e] = bf2f(qv.u[e]);
            }

            int kv[4], mv[4];
#pragma unroll
            for (int jj = 0; jj < 4; ++jj) {
                kv[jj] = pidx  [(size_t)s * NKSP + jj*8 + kj];
                mv[jj] = pimask[(size_t)s * NKSP + jj*8 + kj];
            }

            float sc[4];
#pragma unroll
            for (int jj = 0; jj < 4; ++jj) {
                union { bf16x8 v; ushort u[8]; } kc8;
                kc8.v = *(const bf16x8*)&Kh[(size_t)kv[jj] * NDH + c * 8];
                float d = 0.f;
#pragma unroll
                for (int e = 0; e < 8; ++e) d = fmaf(qf[e], bf2f(kc8.u[e]), d);
                d += __shfl_xor(d, 1);
                d += __shfl_xor(d, 2);
                d += __shfl_xor(d, 4);
                sc[jj] = mv[jj] ? d * SCALE : -INFINITY;
            }

            float mt = fmaxf(fmaxf(sc[0], sc[1]), fmaxf(sc[2], sc[3]));
            mt = fmaxf(mt, __shfl_xor(mt, 8));
            mt = fmaxf(mt, __shfl_xor(mt, 16));
            mt = fmaxf(mt, __shfl_xor(mt, 32));

            float p[4], psum = 0.f;
#pragma unroll
            for (int jj = 0; jj < 4; ++jj) {
                p[jj] = __expf(sc[jj] - mt);
                psum += p[jj];
            }
            psum += __shfl_xor(psum, 8);
            psum += __shfl_xor(psum, 16);
            psum += __shfl_xor(psum, 32);

            float o[8];
#pragma unroll
            for (int e = 0; e < 8; ++e) o[e] = 0.f;
#pragma unroll
            for (int jj = 0; jj < 4; ++jj) {
                union { bf16x8 v; ushort u[8]; } vc8;
                vc8.v = *(const bf16x8*)&Vh[(size_t)kv[jj] * NDH + c * 8];
#pragma unroll
                for (int e = 0; e < 8; ++e)
                    o[e] = fmaf(p[jj], bf2f(vc8.u[e]), o[e]);
            }
#pragma unroll
            for (int e = 0; e < 8; ++e) {
                o[e] += __shfl_xor(o[e], 8);
                o[e] += __shfl_xor(o[e], 16);
                o[e] += __shfl_xor(o[e], 32);
            }

            if (kj == 0) {
                float inv = 1.f / psum;
                union { bf16x8 v; ushort u[8]; } ov;
#pragma unroll
                for (int e = 0; e < 8; ++e) ov.u[e] = f2bf(o[e] * inv);
                *(bf16x8*)&OA[((size_t)b*NS + s)*ND + h*NDH + c*8] = ov.v;
            }
        }
    }
}

// ---------------------------------------------------------------------------
extern "C" void kernel_launch(void* const* d_in, const int* in_sizes, int n_in,
                              void* d_out, int out_size, void* d_ws, size_t ws_size,
                              hipStream_t stream)
{
    const float* x      = (const float*)d_in[0];
    const int*   pmask  = (const int*)  d_in[1];
    const int*   pidx   = (const int*)  d_in[2];
    const int*   pimask = (const int*)  d_in[3];
    const float* u_prev = (const float*)d_in[4];
    const float* Wq     = (const float*)d_in[5];
    const float* bq     = (const float*)d_in[6];
    const float* Wk     = (const float*)d_in[7];
    const float* bk     = (const float*)d_in[8];
    const float* Wv     = (const float*)d_in[9];
    const float* bv     = (const float*)d_in[10];
    const float* Wo     = (const float*)d_in[11];
    const float* bo     = (const float*)d_in[12];
    float* out = (float*)d_out;

    const size_t QSZ = (size_t)NB * NH * NS * NDH;   // 4,194,304 elements
    const size_t WSZ = (size_t)ND * ND;              // 1,048,576 elements
    ushort* xb  = (ushort*)d_ws;        // bf16 x              (8 MB)
    ushort* Qw  = xb  + QSZ;            // bf16 Q (b,h,s,dh)   (8 MB)
    ushort* Kw  = Qw  + QSZ;            // bf16 K              (8 MB)
    ushort* Vw  = Kw  + QSZ;            // bf16 V              (8 MB)
    ushort* Vtw = Vw  + QSZ;            // bf16 V^T (b,h,dh,s) (8 MB)
    ushort* Awb = Vtw + QSZ;            // bf16 attn out       (8 MB)
    ushort* Wqb = Awb + QSZ;            // bf16 weights (2 MB each)
    ushort* Wkb = Wqb + WSZ;
    ushort* Wvb = Wkb + WSZ;
    ushort* Wob = Wvb + WSZ;
    u64*    bmw = (u64*)(Wob + WSZ);    // packed mask (128 KB)

    f2bf_multi<<<dim3(4096, 6), 256, 0, stream>>>(
        x, Wq, Wk, Wv, Wo, pmask, xb, Wqb, Wkb, Wvb, Wob, bmw);

    gemm_qkv<<<dim3(24, 32), 256, 0, stream>>>(
        xb, Wqb, Wkb, Wvb, bq, bk, bv, Qw, Kw, Vw);

    transpose_v<<<1024, 256, 0, stream>>>(Vw, Vtw);

    attn_fused<<<4096, 256, 0, stream>>>(
        Qw, Kw, Vw, Vtw, bmw, pidx, pimask, u_prev, Awb);

    gemm_out<<<dim3(ND/128, (NB*NS)/64), 256, 0, stream>>>(Awb, Wob, bo, out);
}

// Round 14
// 214.669 us; speedup vs baseline: 1.0312x; 1.0312x over previous
//
#include <hip/hip_runtime.h>
#include <hip/hip_bf16.h>
#include <cmath>

#define NB 4
#define NS 1024
#define ND 1024
#define NH 16
#define NDH 64
#define NKSP 32
#define SCALE 0.125f      // 1/sqrt(64)
#define LOG2E 1.44269504f
#define SCALE2 (SCALE * LOG2E)

typedef __attribute__((ext_vector_type(8))) short bf16x8;
typedef __attribute__((ext_vector_type(4))) float f32x4;
typedef unsigned long long u64;

#define AS1 __attribute__((address_space(1)))
#define AS3 __attribute__((address_space(3)))

__device__ __forceinline__ void gl_lds16(const void* g, void* l) {
    __builtin_amdgcn_global_load_lds((const AS1 void*)g, (AS3 void*)l, 16, 0, 0);
}

__device__ __forceinline__ ushort f2bf(float f) {
    union { __hip_bfloat16 h; ushort u; } cv;
    cv.h = __float2bfloat16(f);
    return cv.u;
}
__device__ __forceinline__ float bf2f(ushort u) {
    union { unsigned int i; float f; } cv;
    cv.i = ((unsigned int)u) << 16;
    return cv.f;
}
__device__ __forceinline__ float fexp2(float x) {
    return __builtin_amdgcn_exp2f(x);   // v_exp_f32 (base-2)
}

// ---------------------------------------------------------------------------
// y=0: x->bf16 (4096 blocks); y=1..4: W->bf16 (1024 blocks);
// y=5: pack pmask into bitwords (4096 blocks, one wave per u64 word).
// ---------------------------------------------------------------------------
__global__ __launch_bounds__(256)
void f2bf_multi(const float* __restrict__ x,
                const float* __restrict__ w0, const float* __restrict__ w1,
                const float* __restrict__ w2, const float* __restrict__ w3,
                const int* __restrict__ pm,
                ushort* __restrict__ xo,
                ushort* __restrict__ o0, ushort* __restrict__ o1,
                ushort* __restrict__ o2, ushort* __restrict__ o3,
                u64* __restrict__ bm)
{
    int y = blockIdx.y;
    if (y == 5) {
        int word = blockIdx.x * 4 + (threadIdx.x >> 6);
        int lane = threadIdx.x & 63;
        int row  = word >> 4, wcol = word & 15;
        int v = pm[(size_t)row * NS + wcol * 64 + lane];
        u64 b = __ballot(v != 0);
        if (lane == 0) bm[word] = b;
        return;
    }
    const float* src; ushort* dst; int nblk;
    if (y == 0)      { src = x;  dst = xo; nblk = 4096; }
    else if (y == 1) { src = w0; dst = o0; nblk = 1024; }
    else if (y == 2) { src = w1; dst = o1; nblk = 1024; }
    else if (y == 3) { src = w2; dst = o2; nblk = 1024; }
    else             { src = w3; dst = o3; nblk = 1024; }
    if (blockIdx.x >= (unsigned)nblk) return;
    int i = (blockIdx.x * 256 + threadIdx.x) * 4;
    float4 v = *(const float4*)&src[i];
    ushort4 o;
    o.x = f2bf(v.x); o.y = f2bf(v.y); o.z = f2bf(v.z); o.w = f2bf(v.w);
    *(ushort4*)&dst[i] = o;
}

// ---------------------------------------------------------------------------
// Fused QKV GEMM. grid (24,32): blockIdx.x: [0,8)=Q [8,16)=K [16,24)=V.
// LDS chunk swizzle sigma(c) = c ^ ((c>>3)&7): swizzled global SOURCE +
// linear LDS dest + swizzled fragment read (rule #21).
// r14: V blocks ALSO emit Vt via an LDS-transposed epilogue (two 64x128
// halves through the dead As/Bs region, chunk-XOR swizzle both sides,
// 16B coalesced stores) — replaces the separate transpose_v kernel
// (saves 16MB re-read + 1 launch; r11's global scatter stays dead).
// ---------------------------------------------------------------------------
__global__ __launch_bounds__(256)
void gemm_qkv(const ushort* __restrict__ xb,
              const ushort* __restrict__ Wqb, const ushort* __restrict__ Wkb,
              const ushort* __restrict__ Wvb,
              const float* __restrict__ bq, const float* __restrict__ bk,
              const float* __restrict__ bv,
              ushort* __restrict__ Qo, ushort* __restrict__ Ko,
              ushort* __restrict__ Vo, ushort* __restrict__ Vto)
{
    constexpr int K = ND;
    // As = SM2[0,4096), Bs = SM2[4096,8192) (ushorts). After the K-loop the
    // whole 16KB region is reused as T[64dh][128s] for the Vt transpose.
    __shared__ __attribute__((aligned(16))) ushort SM2[8192];
    ushort* As = SM2;
    ushort* Bs = SM2 + 4096;

    const int tid  = threadIdx.x;
    const int lane = tid & 63, w = tid >> 6;
    const int wm = w >> 1, wn = w & 1;
    const int which = blockIdx.x >> 3;
    const int n0 = (blockIdx.x & 7) * 128;
    const int m0 = blockIdx.y * 128;
    const int quad = lane >> 4, l16 = lane & 15;

    const ushort* W = (which == 0) ? Wqb : (which == 1) ? Wkb : Wvb;
    const float* bias = (which == 0) ? bq : (which == 1) ? bk : bv;
    ushort* Out = (which == 0) ? Qo : (which == 1) ? Ko : Vo;

    f32x4 acc[4][4] = {};

    for (int k0 = 0; k0 < K; k0 += 32) {
        __syncthreads();
#pragma unroll
        for (int u = 0; u < 2; ++u) {
            int t0 = u * 256 + w * 64;
            int t  = t0 + lane;
            int c  = t ^ ((t >> 3) & 7);          // source swizzle
            int row = c >> 2, kc = (c & 3) * 8;
            gl_lds16(xb + (size_t)(m0 + row) * K + k0 + kc, &As[t0 * 8]);
            gl_lds16(W  + (size_t)(n0 + row) * K + k0 + kc, &Bs[t0 * 8]);
        }
        __syncthreads();

        bf16x8 af[4], bfr[4];
#pragma unroll
        for (int mt = 0; mt < 4; ++mt) {
            int cidx = (wm*64 + mt*16 + l16)*4 + quad;
            int p = cidx ^ ((cidx >> 3) & 7);     // swizzled read
            af[mt] = *(const bf16x8*)&As[p * 8];
        }
#pragma unroll
        for (int nt = 0; nt < 4; ++nt) {
            int cidx = (wn*64 + nt*16 + l16)*4 + quad;
            int p = cidx ^ ((cidx >> 3) & 7);
            bfr[nt] = *(const bf16x8*)&Bs[p * 8];
        }
#pragma unroll
        for (int mt = 0; mt < 4; ++mt)
#pragma unroll
            for (int nt = 0; nt < 4; ++nt)
                acc[mt][nt] = __builtin_amdgcn_mfma_f32_16x16x32_bf16(
                    af[mt], bfr[nt], acc[mt][nt], 0, 0, 0);
    }

    // ---- standard row-major epilogue (Q,K,V) ----
#pragma unroll
    for (int nt = 0; nt < 4; ++nt) {
        int n = n0 + wn*64 + nt*16 + l16;
        float bz = bias[n];
        int hh = n >> 6, dh = n & 63;
#pragma unroll
        for (int mt = 0; mt < 4; ++mt) {
#pragma unroll
            for (int rg = 0; rg < 4; ++rg) {
                int m = m0 + wm*64 + mt*16 + quad*4 + rg;
                int b = m >> 10, s = m & (NS - 1);
                Out[(((size_t)(b*NH + hh))*NS + s)*NDH + dh] =
                    f2bf(acc[mt][nt][rg] + bz);
            }
        }
    }

    // ---- Vt epilogue (V blocks only; uniform branch, barriers safe) ----
    if (which == 2) {
        const int bI = m0 >> 10, sbase = m0 & (NS - 1);
        ushort* T = SM2;                          // 64 x 128 ushorts = 16KB
        for (int half = 0; half < 2; ++half) {
            __syncthreads();                      // prior SM2 use done
            if (wn == half) {                     // 2 waves fill 64dh x 128s
#pragma unroll
                for (int nt = 0; nt < 4; ++nt) {
                    int dh = nt*16 + l16;         // 0..63
                    float bz = bias[n0 + half*64 + dh];
#pragma unroll
                    for (int mt = 0; mt < 4; ++mt)
#pragma unroll
                        for (int rg = 0; rg < 4; ++rg) {
                            int m = wm*64 + mt*16 + quad*4 + rg;  // 0..127
                            int cc = (m >> 3) ^ (dh & 7);         // swizzle
                            T[dh*128 + cc*8 + (m & 7)] =
                                f2bf(acc[mt][nt][rg] + bz);
                        }
                }
            }
            __syncthreads();
            int hh = (n0 >> 6) + half;
            ushort* vt = Vto + ((size_t)(bI*NH + hh)) * NDH * NS;
#pragma unroll
            for (int i = 0; i < 4; ++i) {
                int g = i*256 + tid;              // 0..1023
                int dh = g >> 4, sc = g & 15;
                int cs = sc ^ (dh & 7);           // inverse swizzle
                bf16x8 v = *(const bf16x8*)&T[dh*128 + cs*8];
                *(bf16x8*)&vt[(size_t)dh*NS + sbase + sc*8] = v;
            }
        }
    }
}

// ---------------------------------------------------------------------------
// Output GEMM: 64x128 tile -> 512 blocks. Same chunk swizzle as gemm_qkv.
// ---------------------------------------------------------------------------
__global__ __launch_bounds__(256)
void gemm_out(const ushort* __restrict__ A, const ushort* __restrict__ W,
              const float* __restrict__ bias, float* __restrict__ Cout)
{
    constexpr int K = ND;
    __shared__ __attribute__((aligned(16))) ushort As[64 * 32];
    __shared__ __attribute__((aligned(16))) ushort Bs[128 * 32];

    const int tid  = threadIdx.x;
    const int lane = tid & 63, w = tid >> 6;
    const int wm = w & 1, wn = w >> 1;
    const int m0 = blockIdx.y * 64, n0 = blockIdx.x * 128;
    const int quad = lane >> 4, l16 = lane & 15;

    f32x4 acc[2][4] = {};

    for (int k0 = 0; k0 < K; k0 += 32) {
        __syncthreads();
        {
            int t0 = w * 64;
            int t  = t0 + lane;
            int c  = t ^ ((t >> 3) & 7);
            int row = c >> 2, kc = (c & 3) * 8;
            gl_lds16(A + (size_t)(m0 + row) * K + k0 + kc, &As[t0 * 8]);
        }
#pragma unroll
        for (int u = 0; u < 2; ++u) {
            int t0 = u * 256 + w * 64;
            int t  = t0 + lane;
            int c  = t ^ ((t >> 3) & 7);
            int row = c >> 2, kc = (c & 3) * 8;
            gl_lds16(W + (size_t)(n0 + row) * K + k0 + kc, &Bs[t0 * 8]);
        }
        __syncthreads();

        bf16x8 af[2], bfr[4];
#pragma unroll
        for (int mt = 0; mt < 2; ++mt) {
            int cidx = (wm*32 + mt*16 + l16)*4 + quad;
            int p = cidx ^ ((cidx >> 3) & 7);
            af[mt] = *(const bf16x8*)&As[p * 8];
        }
#pragma unroll
        for (int nt = 0; nt < 4; ++nt) {
            int cidx = (wn*64 + nt*16 + l16)*4 + quad;
            int p = cidx ^ ((cidx >> 3) & 7);
            bfr[nt] = *(const bf16x8*)&Bs[p * 8];
        }
#pragma unroll
        for (int mt = 0; mt < 2; ++mt)
#pragma unroll
            for (int nt = 0; nt < 4; ++nt)
                acc[mt][nt] = __builtin_amdgcn_mfma_f32_16x16x32_bf16(
                    af[mt], bfr[nt], acc[mt][nt], 0, 0, 0);
    }

#pragma unroll
    for (int nt = 0; nt < 4; ++nt) {
        int n = n0 + wn*64 + nt*16 + l16;
        float bz = bias[n];
#pragma unroll
        for (int mt = 0; mt < 2; ++mt) {
#pragma unroll
            for (int rg = 0; rg < 4; ++rg) {
                int m = m0 + wm*32 + mt*16 + quad*4 + rg;
                Cout[(size_t)m * ND + n] = acc[mt][nt][rg] + bz;
            }
        }
    }
}

// ---------------------------------------------------------------------------
// attn_dense (r12 exact): 32 q-rows/block, 4 waves = 4-way kt split,
// LDS-K staging + global-V, bm from L2, additive partials + LDS combine.
// ---------------------------------------------------------------------------
#define DSTAGE(T4)                                                            \
    _Pragma("unroll")                                                         \
    for (int u = 0; u < 8; ++u) {                                             \
        int cb = w * 512 + u * 64;                                            \
        int c  = cb + lane;                                                   \
        int tk = c >> 9, c2 = c & 511;                                        \
        int row = c2 >> 3, sub = c2 & 7;                                      \
        const ushort* src = Kh + (((size_t)(((T4)*4 + tk)*64 + row)) << 6)    \
                               + ((sub ^ (row & 7)) << 3);                    \
        gl_lds16(src, KK + (size_t)cb * 8);                                   \
    }

#define DLOADKV(KF, VF, KT)                                                   \
    _Pragma("unroll")                                                         \
    for (int nt = 0; nt < 4; ++nt)                                            \
        _Pragma("unroll")                                                     \
        for (int kk = 0; kk < 2; ++kk) {                                      \
            int rowk = nt*16 + l16;                                           \
            int ck = (kk*4 + quad) ^ (l16 & 7);                               \
            KF[nt][kk] = *(const bf16x8*)&KK[w*4096 + rowk*64 + ck*8];        \
            VF[nt][kk] = *(const bf16x8*)                                     \
                &Vth[(size_t)(nt*16 + l16) * NS + (KT)*64 + kk*32 + quad*8];  \
        }

#define DSTEP(KF, VF, M0, M1)                                                 \
    _Pragma("unroll")                                                         \
    for (int qh = 0; qh < 2; ++qh) {                                          \
        const int qrow = qh*16 + l16;                                         \
        u64 wqm = ((qh == 0) ? (M0) : (M1)) >> (quad * 4);                    \
        f32x4 s_acc[4] = {};                                                  \
        __builtin_amdgcn_s_setprio(1);                                        \
        _Pragma("unroll")                                                     \
        for (int nt = 0; nt < 4; ++nt)                                        \
            _Pragma("unroll")                                                 \
            for (int kk = 0; kk < 2; ++kk)                                    \
                s_acc[nt] = __builtin_amdgcn_mfma_f32_16x16x32_bf16(          \
                    KF[nt][kk], qf[qh][kk], s_acc[nt], 0, 0, 0);              \
        __builtin_amdgcn_s_setprio(0);                                        \
        _Pragma("unroll")                                                     \
        for (int nt = 0; nt < 4; ++nt) {                                      \
            ushort4 pk;                                                       \
            float p0 = fexp2(fmaf(s_acc[nt][0], SCALE2,                       \
                 ((wqm >> (nt*16 + 0)) & 1ULL) ? 0.f : nlam2));               \
            float p1 = fexp2(fmaf(s_acc[nt][1], SCALE2,                       \
                 ((wqm >> (nt*16 + 1)) & 1ULL) ? 0.f : nlam2));               \
            float p2 = fexp2(fmaf(s_acc[nt][2], SCALE2,                       \
                 ((wqm >> (nt*16 + 2)) & 1ULL) ? 0.f : nlam2));               \
            float p3 = fexp2(fmaf(s_acc[nt][3], SCALE2,                       \
                 ((wqm >> (nt*16 + 3)) & 1ULL) ? 0.f : nlam2));               \
            pk.x = f2bf(p0); pk.y = f2bf(p1);                                 \
            pk.z = f2bf(p2); pk.w = f2bf(p3);                                 \
            *(ushort4*)&Ps[w*2304 + qrow*72 + nt*16 + quad*4] = pk;           \
        }                                                                     \
        bf16x8 pf[2];                                                         \
        _Pragma("unroll")                                                     \
        for (int kk = 0; kk < 2; ++kk)                                        \
            pf[kk] = *(const bf16x8*)&Ps[w*2304 + qrow*72 + kk*32 + quad*8];  \
        __builtin_amdgcn_s_setprio(1);                                        \
        _Pragma("unroll")                                                     \
        for (int kk = 0; kk < 2; ++kk) {                                      \
            l_acc[qh] = __builtin_amdgcn_mfma_f32_16x16x32_bf16(              \
                pf[kk], ones.v, l_acc[qh], 0, 0, 0);                          \
            _Pragma("unroll")                                                 \
            for (int nt = 0; nt < 4; ++nt)                                    \
                o_acc[qh][nt] = __builtin_amdgcn_mfma_f32_16x16x32_bf16(      \
                    pf[kk], VF[nt][kk], o_acc[qh][nt], 0, 0, 0);              \
        }                                                                     \
        __builtin_amdgcn_s_setprio(0);                                        \
    }

__global__ __launch_bounds__(256)
void attn_dense(const ushort* __restrict__ Qb, const ushort* __restrict__ Kb,
                const ushort* __restrict__ Vt, const u64* __restrict__ bm,
                const float* __restrict__ u_prev, ushort* __restrict__ OA)
{
    __shared__ __attribute__((aligned(16))) ushort SM[25600];
    ushort* KK = SM;
    ushort* Ps = SM + 16384;

    const int tid  = threadIdx.x;
    const int lane = tid & 63, w = tid >> 6;
    const int quad = lane >> 4, l16 = lane & 15;

    float lams[4];
#pragma unroll
    for (int i = 0; i < 4; ++i) lams[i] = 10.0f * __expf(-5.0f * u_prev[i]);
    int dl[4], nd = 0;
#pragma unroll
    for (int i = 0; i < 4; ++i) if (lams[i] < 1.0f) dl[nd++] = i;

    const int id = blockIdx.x;                    // grid 2048
    if (id >= nd * 512) return;

    int xcd = id & 7, j = id >> 3;
    int nh2 = 2 * nd;
    int hi = j % nh2, qt = j / nh2;
    int gh = hi * 8 + xcd;
    const int b = dl[gh >> 4], h = gh & 15;
    const int s0 = qt * 32;
    const float nlam2 = -lams[b] * LOG2E;

    const size_t bh = (size_t)b * NH + h;
    const ushort* Qh  = Qb + bh * NS * NDH;
    const ushort* Kh  = Kb + bh * NS * NDH;
    const ushort* Vth = Vt + bh * NDH * NS;

    bf16x8 qf[2][2];
#pragma unroll
    for (int qh = 0; qh < 2; ++qh)
#pragma unroll
        for (int kk = 0; kk < 2; ++kk)
            qf[qh][kk] = *(const bf16x8*)
                &Qh[(size_t)(s0 + qh*16 + l16) * NDH + kk*32 + quad*8];

    union { bf16x8 v; ushort s[8]; } ones;
#pragma unroll
    for (int i = 0; i < 8; ++i) ones.s[i] = 0x3F80;

    f32x4 o_acc[2][4] = {};
    f32x4 l_acc[2] = {};

    for (int t = 0; t < 4; ++t) {
        if (t) __syncthreads();
        DSTAGE(t);
        const int kt = 4 * t + w;
        u64 m0 = bm[(size_t)(s0 +  0 + l16) * 16 + kt];
        u64 m1 = bm[(size_t)(s0 + 16 + l16) * 16 + kt];
        __syncthreads();
        bf16x8 kf[4][2], vf[4][2];
        DLOADKV(kf, vf, kt);
        DSTEP(kf, vf, m0, m1);
    }
    __syncthreads();

    float* POUT = (float*)SM;
    if (w != 0) {
        int base = (w - 1) * 2560;
#pragma unroll
        for (int qh = 0; qh < 2; ++qh) {
#pragma unroll
            for (int nt = 0; nt < 4; ++nt)
#pragma unroll
                for (int rg = 0; rg < 4; ++rg)
                    POUT[base + (qh*16 + nt*4 + rg)*64 + lane] =
                        o_acc[qh][nt][rg];
#pragma unroll
            for (int rg = 0; rg < 4; ++rg)
                POUT[base + (32 + qh*4 + rg)*64 + lane] = l_acc[qh][rg];
        }
    }
    __syncthreads();
    if (w == 0) {
#pragma unroll
        for (int s = 0; s < 3; ++s) {
            int base = s * 2560;
#pragma unroll
            for (int qh = 0; qh < 2; ++qh) {
#pragma unroll
                for (int nt = 0; nt < 4; ++nt)
#pragma unroll
                    for (int rg = 0; rg < 4; ++rg)
                        o_acc[qh][nt][rg] +=
                            POUT[base + (qh*16 + nt*4 + rg)*64 + lane];
#pragma unroll
                for (int rg = 0; rg < 4; ++rg)
                    l_acc[qh][rg] += POUT[base + (32 + qh*4 + rg)*64 + lane];
            }
        }
#pragma unroll
        for (int qh = 0; qh < 2; ++qh) {
            float inv[4];
#pragma unroll
            for (int rg = 0; rg < 4; ++rg) inv[rg] = 1.f / l_acc[qh][rg];
#pragma unroll
            for (int nt = 0; nt < 4; ++nt)
#pragma unroll
                for (int rg = 0; rg < 4; ++rg) {
                    int m = qh*16 + quad*4 + rg;
                    OA[((size_t)b*NS + s0 + m)*ND + h*NDH + nt*16 + l16] =
                        f2bf(o_acc[qh][nt][rg] * inv[rg]);
                }
        }
    }
}

// ---------------------------------------------------------------------------
// attn_sparse (r12 exact): coalesced gather, wave = (kj8 x c8), no LDS.
// ---------------------------------------------------------------------------
__global__ __launch_bounds__(256)
void attn_sparse(const ushort* __restrict__ Qb, const ushort* __restrict__ Kb,
                 const ushort* __restrict__ Vb,
                 const int* __restrict__ pidx, const int* __restrict__ pimask,
                 const float* __restrict__ u_prev, ushort* __restrict__ OA)
{
    const int tid  = threadIdx.x;
    const int lane = tid & 63, w = tid >> 6;
    const int kj = lane >> 3;
    const int c  = lane & 7;

    float lams[4];
#pragma unroll
    for (int i = 0; i < 4; ++i) lams[i] = 10.0f * __expf(-5.0f * u_prev[i]);
    int sl[4], ns = 0;
#pragma unroll
    for (int i = 0; i < 4; ++i) if (lams[i] >= 1.0f) sl[ns++] = i;

    const int id = blockIdx.x;                    // grid 4096
    if (id >= ns * 1024) return;

    int xcd = id & 7, j = id >> 3;
    int nh2 = 2 * ns;
    int hi = j % nh2, qt = j / nh2;
    int gh = hi * 8 + xcd;
    const int b = sl[gh >> 4], h = gh & 15;
    const int s0 = qt * 16 + w * 4;

    const size_t bh = (size_t)b * NH + h;
    const ushort* Qh = Qb + bh * NS * NDH;
    const ushort* Kh = Kb + bh * NS * NDH;
    const ushort* Vh = Vb + bh * NS * NDH;

    for (int r = 0; r < 4; ++r) {
        const int s = s0 + r;

        float qf[8];
        {
            union { bf16x8 v; ushort u[8]; } qv;
            qv.v = *(const bf16x8*)&Qh[(size_t)s * NDH + c * 8];
#pragma unroll
            for (int e = 0; e < 8; ++e) qf[e] = bf2f(qv.u[e]);
        }

        int kv[4], mv[4];
#pragma unroll
        for (int jj = 0; jj < 4; ++jj) {
            kv[jj] = pidx  [(size_t)s * NKSP + jj*8 + kj];
            mv[jj] = pimask[(size_t)s * NKSP + jj*8 + kj];
        }

        float sc[4];
#pragma unroll
        for (int jj = 0; jj < 4; ++jj) {
            union { bf16x8 v; ushort u[8]; } kc8;
            kc8.v = *(const bf16x8*)&Kh[(size_t)kv[jj] * NDH + c * 8];
            float d = 0.f;
#pragma unroll
            for (int e = 0; e < 8; ++e) d = fmaf(qf[e], bf2f(kc8.u[e]), d);
            d += __shfl_xor(d, 1);
            d += __shfl_xor(d, 2);
            d += __shfl_xor(d, 4);
            sc[jj] = mv[jj] ? d * SCALE : -INFINITY;
        }

        float mt = fmaxf(fmaxf(sc[0], sc[1]), fmaxf(sc[2], sc[3]));
        mt = fmaxf(mt, __shfl_xor(mt, 8));
        mt = fmaxf(mt, __shfl_xor(mt, 16));
        mt = fmaxf(mt, __shfl_xor(mt, 32));

        float p[4], psum = 0.f;
#pragma unroll
        for (int jj = 0; jj < 4; ++jj) {
            p[jj] = __expf(sc[jj] - mt);
            psum += p[jj];
        }
        psum += __shfl_xor(psum, 8);
        psum += __shfl_xor(psum, 16);
        psum += __shfl_xor(psum, 32);

        float o[8];
#pragma unroll
        for (int e = 0; e < 8; ++e) o[e] = 0.f;
#pragma unroll
        for (int jj = 0; jj < 4; ++jj) {
            union { bf16x8 v; ushort u[8]; } vc8;
            vc8.v = *(const bf16x8*)&Vh[(size_t)kv[jj] * NDH + c * 8];
#pragma unroll
            for (int e = 0; e < 8; ++e)
                o[e] = fmaf(p[jj], bf2f(vc8.u[e]), o[e]);
        }
#pragma unroll
        for (int e = 0; e < 8; ++e) {
            o[e] += __shfl_xor(o[e], 8);
            o[e] += __shfl_xor(o[e], 16);
            o[e] += __shfl_xor(o[e], 32);
        }

        if (kj == 0) {
            float inv = 1.f / psum;
            union { bf16x8 v; ushort u[8]; } ov;
#pragma unroll
            for (int e = 0; e < 8; ++e) ov.u[e] = f2bf(o[e] * inv);
            *(bf16x8*)&OA[((size_t)b*NS + s)*ND + h*NDH + c*8] = ov.v;
        }
    }
}

// ---------------------------------------------------------------------------
extern "C" void kernel_launch(void* const* d_in, const int* in_sizes, int n_in,
                              void* d_out, int out_size, void* d_ws, size_t ws_size,
                              hipStream_t stream)
{
    const float* x      = (const float*)d_in[0];
    const int*   pmask  = (const int*)  d_in[1];
    const int*   pidx   = (const int*)  d_in[2];
    const int*   pimask = (const int*)  d_in[3];
    const float* u_prev = (const float*)d_in[4];
    const float* Wq     = (const float*)d_in[5];
    const float* bq     = (const float*)d_in[6];
    const float* Wk     = (const float*)d_in[7];
    const float* bk     = (const float*)d_in[8];
    const float* Wv     = (const float*)d_in[9];
    const float* bv     = (const float*)d_in[10];
    const float* Wo     = (const float*)d_in[11];
    const float* bo     = (const float*)d_in[12];
    float* out = (float*)d_out;

    const size_t QSZ = (size_t)NB * NH * NS * NDH;   // 4,194,304 elements
    const size_t WSZ = (size_t)ND * ND;              // 1,048,576 elements
    ushort* xb  = (ushort*)d_ws;        // bf16 x              (8 MB)
    ushort* Qw  = xb  + QSZ;            // bf16 Q (b,h,s,dh)   (8 MB)
    ushort* Kw  = Qw  + QSZ;            // bf16 K              (8 MB)
    ushort* Vw  = Kw  + QSZ;            // bf16 V              (8 MB)
    ushort* Vtw = Vw  + QSZ;            // bf16 V^T (b,h,dh,s) (8 MB)
    ushort* Awb = Vtw + QSZ;            // bf16 attn out       (8 MB)
    ushort* Wqb = Awb + QSZ;            // bf16 weights (2 MB each)
    ushort* Wkb = Wqb + WSZ;
    ushort* Wvb = Wkb + WSZ;
    ushort* Wob = Wvb + WSZ;
    u64*    bmw = (u64*)(Wob + WSZ);    // packed mask (128 KB)

    f2bf_multi<<<dim3(4096, 6), 256, 0, stream>>>(
        x, Wq, Wk, Wv, Wo, pmask, xb, Wqb, Wkb, Wvb, Wob, bmw);

    gemm_qkv<<<dim3(24, 32), 256, 0, stream>>>(
        xb, Wqb, Wkb, Wvb, bq, bk, bv, Qw, Kw, Vw, Vtw);

    attn_dense<<<2048, 256, 0, stream>>>(
        Qw, Kw, Vtw, bmw, u_prev, Awb);

    attn_sparse<<<4096, 256, 0, stream>>>(
        Qw, Kw, Vw, pidx, pimask, u_prev, Awb);

    gemm_out<<<dim3(ND/128, (NB*NS)/64), 256, 0, stream>>>(Awb, Wob, bo, out);
}

// Round 15
// 202.057 us; speedup vs baseline: 1.0956x; 1.0624x over previous
//
#include <hip/hip_runtime.h>
#include <hip/hip_bf16.h>
#include <cmath>

#define NB 4
#define NS 1024
#define ND 1024
#define NH 16
#define NDH 64
#define NKSP 32
#define SCALE 0.125f      // 1/sqrt(64)
#define LOG2E 1.44269504f
#define SCALE2 (SCALE * LOG2E)

typedef __attribute__((ext_vector_type(8))) short bf16x8;
typedef __attribute__((ext_vector_type(4))) float f32x4;
typedef unsigned long long u64;

#define AS1 __attribute__((address_space(1)))
#define AS3 __attribute__((address_space(3)))

__device__ __forceinline__ void gl_lds16(const void* g, void* l) {
    __builtin_amdgcn_global_load_lds((const AS1 void*)g, (AS3 void*)l, 16, 0, 0);
}

__device__ __forceinline__ ushort f2bf(float f) {
    union { __hip_bfloat16 h; ushort u; } cv;
    cv.h = __float2bfloat16(f);
    return cv.u;
}
__device__ __forceinline__ float bf2f(ushort u) {
    union { unsigned int i; float f; } cv;
    cv.i = ((unsigned int)u) << 16;
    return cv.f;
}
__device__ __forceinline__ float fexp2(float x) {
    return __builtin_amdgcn_exp2f(x);   // v_exp_f32 (base-2)
}

// ---------------------------------------------------------------------------
// y=0: x->bf16 (4096 blocks); y=1..4: W->bf16 (1024 blocks);
// y=5: pack pmask into bitwords (4096 blocks, one wave per u64 word).
// ---------------------------------------------------------------------------
__global__ __launch_bounds__(256)
void f2bf_multi(const float* __restrict__ x,
                const float* __restrict__ w0, const float* __restrict__ w1,
                const float* __restrict__ w2, const float* __restrict__ w3,
                const int* __restrict__ pm,
                ushort* __restrict__ xo,
                ushort* __restrict__ o0, ushort* __restrict__ o1,
                ushort* __restrict__ o2, ushort* __restrict__ o3,
                u64* __restrict__ bm)
{
    int y = blockIdx.y;
    if (y == 5) {
        int word = blockIdx.x * 4 + (threadIdx.x >> 6);
        int lane = threadIdx.x & 63;
        int row  = word >> 4, wcol = word & 15;
        int v = pm[(size_t)row * NS + wcol * 64 + lane];
        u64 b = __ballot(v != 0);
        if (lane == 0) bm[word] = b;
        return;
    }
    const float* src; ushort* dst; int nblk;
    if (y == 0)      { src = x;  dst = xo; nblk = 4096; }
    else if (y == 1) { src = w0; dst = o0; nblk = 1024; }
    else if (y == 2) { src = w1; dst = o1; nblk = 1024; }
    else if (y == 3) { src = w2; dst = o2; nblk = 1024; }
    else             { src = w3; dst = o3; nblk = 1024; }
    if (blockIdx.x >= (unsigned)nblk) return;
    int i = (blockIdx.x * 256 + threadIdx.x) * 4;
    float4 v = *(const float4*)&src[i];
    ushort4 o;
    o.x = f2bf(v.x); o.y = f2bf(v.y); o.z = f2bf(v.z); o.w = f2bf(v.w);
    *(ushort4*)&dst[i] = o;
}

// ---------------------------------------------------------------------------
// Fused QKV GEMM. grid (24,32): blockIdx.x: [0,8)=Q [8,16)=K [16,24)=V.
// r15: BK 32 -> 64 (ONLY change vs r12). Halves the K-loop barrier count
// (32 -> 16 vmcnt-drain stalls); 32 MFMA vs 16 ds_read_b128 per step.
// Swizzle = attn-proven row-XOR (rule #21, both-sides): LDS chunk
// (row,sub) holds global chunk (row, sub^(row&7)); fragment read uses
// ck = (kk*4+quad) ^ (l16&7). LDS 32KB -> still 3 blocks/CU at 768 grid.
// ---------------------------------------------------------------------------
__global__ __launch_bounds__(256)
void gemm_qkv(const ushort* __restrict__ xb,
              const ushort* __restrict__ Wqb, const ushort* __restrict__ Wkb,
              const ushort* __restrict__ Wvb,
              const float* __restrict__ bq, const float* __restrict__ bk,
              const float* __restrict__ bv,
              ushort* __restrict__ Qo, ushort* __restrict__ Ko,
              ushort* __restrict__ Vo)
{
    constexpr int K = ND;
    __shared__ __attribute__((aligned(16))) ushort As[128 * 64];
    __shared__ __attribute__((aligned(16))) ushort Bs[128 * 64];

    const int tid  = threadIdx.x;
    const int lane = tid & 63, w = tid >> 6;
    const int wm = w >> 1, wn = w & 1;
    const int which = blockIdx.x >> 3;
    const int n0 = (blockIdx.x & 7) * 128;
    const int m0 = blockIdx.y * 128;
    const int quad = lane >> 4, l16 = lane & 15;

    const ushort* W = (which == 0) ? Wqb : (which == 1) ? Wkb : Wvb;
    const float* bias = (which == 0) ? bq : (which == 1) ? bk : bv;
    ushort* Out = (which == 0) ? Qo : (which == 1) ? Ko : Vo;

    f32x4 acc[4][4] = {};

    for (int k0 = 0; k0 < K; k0 += 64) {
        __syncthreads();
        // stage 128x64 A and B tiles (1024 chunks each; wave w: 256/tile)
#pragma unroll
        for (int u = 0; u < 4; ++u) {
            int cb = w * 256 + u * 64;
            int c  = cb + lane;
            int row = c >> 3, sub = c & 7;
            int kc = (sub ^ (row & 7)) * 8;       // source swizzle
            gl_lds16(xb + (size_t)(m0 + row) * K + k0 + kc, &As[cb * 8]);
            gl_lds16(W  + (size_t)(n0 + row) * K + k0 + kc, &Bs[cb * 8]);
        }
        __syncthreads();

        bf16x8 af[4][2], bfr[4][2];
#pragma unroll
        for (int mt = 0; mt < 4; ++mt) {
            int row = wm*64 + mt*16 + l16;        // row&7 == l16&7
#pragma unroll
            for (int kk = 0; kk < 2; ++kk) {
                int ck = (kk*4 + quad) ^ (l16 & 7);
                af[mt][kk] = *(const bf16x8*)&As[row*64 + ck*8];
            }
        }
#pragma unroll
        for (int nt = 0; nt < 4; ++nt) {
            int row = wn*64 + nt*16 + l16;
#pragma unroll
            for (int kk = 0; kk < 2; ++kk) {
                int ck = (kk*4 + quad) ^ (l16 & 7);
                bfr[nt][kk] = *(const bf16x8*)&Bs[row*64 + ck*8];
            }
        }
#pragma unroll
        for (int mt = 0; mt < 4; ++mt)
#pragma unroll
            for (int nt = 0; nt < 4; ++nt)
#pragma unroll
                for (int kk = 0; kk < 2; ++kk)
                    acc[mt][nt] = __builtin_amdgcn_mfma_f32_16x16x32_bf16(
                        af[mt][kk], bfr[nt][kk], acc[mt][nt], 0, 0, 0);
    }

#pragma unroll
    for (int nt = 0; nt < 4; ++nt) {
        int n = n0 + wn*64 + nt*16 + l16;
        float bz = bias[n];
        int hh = n >> 6, dh = n & 63;
#pragma unroll
        for (int mt = 0; mt < 4; ++mt) {
#pragma unroll
            for (int rg = 0; rg < 4; ++rg) {
                int m = m0 + wm*64 + mt*16 + quad*4 + rg;
                int b = m >> 10, s = m & (NS - 1);
                Out[(((size_t)(b*NH + hh))*NS + s)*NDH + dh] =
                    f2bf(acc[mt][nt][rg] + bz);
            }
        }
    }
}

// ---------------------------------------------------------------------------
// V transpose: [b,h,s,dh] -> [b,h,dh,s], 64x64 tiles, XOR-swizzled LDS,
// coalesced 16B global on both sides. 1024 blocks x 256 thr, 8KB LDS.
// (r12 exact — r14 proved folding this into gemm_qkv regresses.)
// ---------------------------------------------------------------------------
__global__ __launch_bounds__(256)
void transpose_v(const ushort* __restrict__ V, ushort* __restrict__ Vt)
{
    __shared__ __attribute__((aligned(16))) ushort T[64 * 64];

    const int t  = threadIdx.x;
    const int bh = blockIdx.x >> 4;               // 0..63 (b*16+h)
    const int st = blockIdx.x & 15;               // s-tile
    const ushort* Vh  = V  + (size_t)bh * NS * NDH + (size_t)st * 64 * NDH;
    ushort*       Vth = Vt + (size_t)bh * NDH * NS + st * 64;

#pragma unroll
    for (int i = 0; i < 2; ++i) {
        int g = i * 256 + t;                      // 0..511
        int srow = g >> 3, sub = g & 7;
        union { bf16x8 v; ushort u[8]; } x;
        x.v = *(const bf16x8*)&Vh[(size_t)srow * NDH + sub * 8];
#pragma unroll
        for (int e = 0; e < 8; ++e) {
            int dh = sub * 8 + e;                 // dh>>3 == sub
            T[dh*64 + (((srow >> 3) ^ sub) * 8) + (srow & 7)] = x.u[e];
        }
    }
    __syncthreads();
#pragma unroll
    for (int i = 0; i < 2; ++i) {
        int g = i * 256 + t;
        int dh = g >> 3, sc = g & 7;
        bf16x8 v = *(const bf16x8*)&T[dh*64 + ((sc ^ (dh >> 3)) * 8)];
        *(bf16x8*)&Vth[(size_t)dh * NS + sc * 8] = v;
    }
}

// ---------------------------------------------------------------------------
// Output GEMM: 64x128 tile -> 512 blocks. r12 exact (chunk swizzle).
// ---------------------------------------------------------------------------
__global__ __launch_bounds__(256)
void gemm_out(const ushort* __restrict__ A, const ushort* __restrict__ W,
              const float* __restrict__ bias, float* __restrict__ Cout)
{
    constexpr int K = ND;
    __shared__ __attribute__((aligned(16))) ushort As[64 * 32];
    __shared__ __attribute__((aligned(16))) ushort Bs[128 * 32];

    const int tid  = threadIdx.x;
    const int lane = tid & 63, w = tid >> 6;
    const int wm = w & 1, wn = w >> 1;
    const int m0 = blockIdx.y * 64, n0 = blockIdx.x * 128;
    const int quad = lane >> 4, l16 = lane & 15;

    f32x4 acc[2][4] = {};

    for (int k0 = 0; k0 < K; k0 += 32) {
        __syncthreads();
        {
            int t0 = w * 64;
            int t  = t0 + lane;
            int c  = t ^ ((t >> 3) & 7);
            int row = c >> 2, kc = (c & 3) * 8;
            gl_lds16(A + (size_t)(m0 + row) * K + k0 + kc, &As[t0 * 8]);
        }
#pragma unroll
        for (int u = 0; u < 2; ++u) {
            int t0 = u * 256 + w * 64;
            int t  = t0 + lane;
            int c  = t ^ ((t >> 3) & 7);
            int row = c >> 2, kc = (c & 3) * 8;
            gl_lds16(W + (size_t)(n0 + row) * K + k0 + kc, &Bs[t0 * 8]);
        }
        __syncthreads();

        bf16x8 af[2], bfr[4];
#pragma unroll
        for (int mt = 0; mt < 2; ++mt) {
            int cidx = (wm*32 + mt*16 + l16)*4 + quad;
            int p = cidx ^ ((cidx >> 3) & 7);
            af[mt] = *(const bf16x8*)&As[p * 8];
        }
#pragma unroll
        for (int nt = 0; nt < 4; ++nt) {
            int cidx = (wn*64 + nt*16 + l16)*4 + quad;
            int p = cidx ^ ((cidx >> 3) & 7);
            bfr[nt] = *(const bf16x8*)&Bs[p * 8];
        }
#pragma unroll
        for (int mt = 0; mt < 2; ++mt)
#pragma unroll
            for (int nt = 0; nt < 4; ++nt)
                acc[mt][nt] = __builtin_amdgcn_mfma_f32_16x16x32_bf16(
                    af[mt], bfr[nt], acc[mt][nt], 0, 0, 0);
    }

#pragma unroll
    for (int nt = 0; nt < 4; ++nt) {
        int n = n0 + wn*64 + nt*16 + l16;
        float bz = bias[n];
#pragma unroll
        for (int mt = 0; mt < 2; ++mt) {
#pragma unroll
            for (int rg = 0; rg < 4; ++rg) {
                int m = m0 + wm*32 + mt*16 + quad*4 + rg;
                Cout[(size_t)m * ND + n] = acc[mt][nt][rg] + bz;
            }
        }
    }
}

// ---------------------------------------------------------------------------
// attn_dense (r12 exact): 32 q-rows/block, 4 waves = 4-way kt split,
// LDS-K staging + global-V, bm from L2, additive partials + LDS combine.
// ---------------------------------------------------------------------------
#define DSTAGE(T4)                                                            \
    _Pragma("unroll")                                                         \
    for (int u = 0; u < 8; ++u) {                                             \
        int cb = w * 512 + u * 64;                                            \
        int c  = cb + lane;                                                   \
        int tk = c >> 9, c2 = c & 511;                                        \
        int row = c2 >> 3, sub = c2 & 7;                                      \
        const ushort* src = Kh + (((size_t)(((T4)*4 + tk)*64 + row)) << 6)    \
                               + ((sub ^ (row & 7)) << 3);                    \
        gl_lds16(src, KK + (size_t)cb * 8);                                   \
    }

#define DLOADKV(KF, VF, KT)                                                   \
    _Pragma("unroll")                                                         \
    for (int nt = 0; nt < 4; ++nt)                                            \
        _Pragma("unroll")                                                     \
        for (int kk = 0; kk < 2; ++kk) {                                      \
            int rowk = nt*16 + l16;                                           \
            int ck = (kk*4 + quad) ^ (l16 & 7);                               \
            KF[nt][kk] = *(const bf16x8*)&KK[w*4096 + rowk*64 + ck*8];        \
            VF[nt][kk] = *(const bf16x8*)                                     \
                &Vth[(size_t)(nt*16 + l16) * NS + (KT)*64 + kk*32 + quad*8];  \
        }

#define DSTEP(KF, VF, M0, M1)                                                 \
    _Pragma("unroll")                                                         \
    for (int qh = 0; qh < 2; ++qh) {                                          \
        const int qrow = qh*16 + l16;                                         \
        u64 wqm = ((qh == 0) ? (M0) : (M1)) >> (quad * 4);                    \
        f32x4 s_acc[4] = {};                                                  \
        __builtin_amdgcn_s_setprio(1);                                        \
        _Pragma("unroll")                                                     \
        for (int nt = 0; nt < 4; ++nt)                                        \
            _Pragma("unroll")                                                 \
            for (int kk = 0; kk < 2; ++kk)                                    \
                s_acc[nt] = __builtin_amdgcn_mfma_f32_16x16x32_bf16(          \
                    KF[nt][kk], qf[qh][kk], s_acc[nt], 0, 0, 0);              \
        __builtin_amdgcn_s_setprio(0);                                        \
        _Pragma("unroll")                                                     \
        for (int nt = 0; nt < 4; ++nt) {                                      \
            ushort4 pk;                                                       \
            float p0 = fexp2(fmaf(s_acc[nt][0], SCALE2,                       \
                 ((wqm >> (nt*16 + 0)) & 1ULL) ? 0.f : nlam2));               \
            float p1 = fexp2(fmaf(s_acc[nt][1], SCALE2,                       \
                 ((wqm >> (nt*16 + 1)) & 1ULL) ? 0.f : nlam2));               \
            float p2 = fexp2(fmaf(s_acc[nt][2], SCALE2,                       \
                 ((wqm >> (nt*16 + 2)) & 1ULL) ? 0.f : nlam2));               \
            float p3 = fexp2(fmaf(s_acc[nt][3], SCALE2,                       \
                 ((wqm >> (nt*16 + 3)) & 1ULL) ? 0.f : nlam2));               \
            pk.x = f2bf(p0); pk.y = f2bf(p1);                                 \
            pk.z = f2bf(p2); pk.w = f2bf(p3);                                 \
            *(ushort4*)&Ps[w*2304 + qrow*72 + nt*16 + quad*4] = pk;           \
        }                                                                     \
        bf16x8 pf[2];                                                         \
        _Pragma("unroll")                                                     \
        for (int kk = 0; kk < 2; ++kk)                                        \
            pf[kk] = *(const bf16x8*)&Ps[w*2304 + qrow*72 + kk*32 + quad*8];  \
        __builtin_amdgcn_s_setprio(1);                                        \
        _Pragma("unroll")                                                     \
        for (int kk = 0; kk < 2; ++kk) {                                      \
            l_acc[qh] = __builtin_amdgcn_mfma_f32_16x16x32_bf16(              \
                pf[kk], ones.v, l_acc[qh], 0, 0, 0);                          \
            _Pragma("unroll")                                                 \
            for (int nt = 0; nt < 4; ++nt)                                    \
                o_acc[qh][nt] = __builtin_amdgcn_mfma_f32_16x16x32_bf16(      \
                    pf[kk], VF[nt][kk], o_acc[qh][nt], 0, 0, 0);              \
        }                                                                     \
        __builtin_amdgcn_s_setprio(0);                                        \
    }

__global__ __launch_bounds__(256)
void attn_dense(const ushort* __restrict__ Qb, const ushort* __restrict__ Kb,
                const ushort* __restrict__ Vt, const u64* __restrict__ bm,
                const float* __restrict__ u_prev, ushort* __restrict__ OA)
{
    __shared__ __attribute__((aligned(16))) ushort SM[25600];
    ushort* KK = SM;
    ushort* Ps = SM + 16384;

    const int tid  = threadIdx.x;
    const int lane = tid & 63, w = tid >> 6;
    const int quad = lane >> 4, l16 = lane & 15;

    float lams[4];
#pragma unroll
    for (int i = 0; i < 4; ++i) lams[i] = 10.0f * __expf(-5.0f * u_prev[i]);
    int dl[4], nd = 0;
#pragma unroll
    for (int i = 0; i < 4; ++i) if (lams[i] < 1.0f) dl[nd++] = i;

    const int id = blockIdx.x;                    // grid 2048
    if (id >= nd * 512) return;

    int xcd = id & 7, j = id >> 3;
    int nh2 = 2 * nd;
    int hi = j % nh2, qt = j / nh2;
    int gh = hi * 8 + xcd;
    const int b = dl[gh >> 4], h = gh & 15;
    const int s0 = qt * 32;
    const float nlam2 = -lams[b] * LOG2E;

    const size_t bh = (size_t)b * NH + h;
    const ushort* Qh  = Qb + bh * NS * NDH;
    const ushort* Kh  = Kb + bh * NS * NDH;
    const ushort* Vth = Vt + bh * NDH * NS;

    bf16x8 qf[2][2];
#pragma unroll
    for (int qh = 0; qh < 2; ++qh)
#pragma unroll
        for (int kk = 0; kk < 2; ++kk)
            qf[qh][kk] = *(const bf16x8*)
                &Qh[(size_t)(s0 + qh*16 + l16) * NDH + kk*32 + quad*8];

    union { bf16x8 v; ushort s[8]; } ones;
#pragma unroll
    for (int i = 0; i < 8; ++i) ones.s[i] = 0x3F80;

    f32x4 o_acc[2][4] = {};
    f32x4 l_acc[2] = {};

    for (int t = 0; t < 4; ++t) {
        if (t) __syncthreads();
        DSTAGE(t);
        const int kt = 4 * t + w;
        u64 m0 = bm[(size_t)(s0 +  0 + l16) * 16 + kt];
        u64 m1 = bm[(size_t)(s0 + 16 + l16) * 16 + kt];
        __syncthreads();
        bf16x8 kf[4][2], vf[4][2];
        DLOADKV(kf, vf, kt);
        DSTEP(kf, vf, m0, m1);
    }
    __syncthreads();

    float* POUT = (float*)SM;
    if (w != 0) {
        int base = (w - 1) * 2560;
#pragma unroll
        for (int qh = 0; qh < 2; ++qh) {
#pragma unroll
            for (int nt = 0; nt < 4; ++nt)
#pragma unroll
                for (int rg = 0; rg < 4; ++rg)
                    POUT[base + (qh*16 + nt*4 + rg)*64 + lane] =
                        o_acc[qh][nt][rg];
#pragma unroll
            for (int rg = 0; rg < 4; ++rg)
                POUT[base + (32 + qh*4 + rg)*64 + lane] = l_acc[qh][rg];
        }
    }
    __syncthreads();
    if (w == 0) {
#pragma unroll
        for (int s = 0; s < 3; ++s) {
            int base = s * 2560;
#pragma unroll
            for (int qh = 0; qh < 2; ++qh) {
#pragma unroll
                for (int nt = 0; nt < 4; ++nt)
#pragma unroll
                    for (int rg = 0; rg < 4; ++rg)
                        o_acc[qh][nt][rg] +=
                            POUT[base + (qh*16 + nt*4 + rg)*64 + lane];
#pragma unroll
                for (int rg = 0; rg < 4; ++rg)
                    l_acc[qh][rg] += POUT[base + (32 + qh*4 + rg)*64 + lane];
            }
        }
#pragma unroll
        for (int qh = 0; qh < 2; ++qh) {
            float inv[4];
#pragma unroll
            for (int rg = 0; rg < 4; ++rg) inv[rg] = 1.f / l_acc[qh][rg];
#pragma unroll
            for (int nt = 0; nt < 4; ++nt)
#pragma unroll
                for (int rg = 0; rg < 4; ++rg) {
                    int m = qh*16 + quad*4 + rg;
                    OA[((size_t)b*NS + s0 + m)*ND + h*NDH + nt*16 + l16] =
                        f2bf(o_acc[qh][nt][rg] * inv[rg]);
                }
        }
    }
}

// ---------------------------------------------------------------------------
// attn_sparse (r12 exact): coalesced gather, wave = (kj8 x c8), no LDS.
// ---------------------------------------------------------------------------
__global__ __launch_bounds__(256)
void attn_sparse(const ushort* __restrict__ Qb, const ushort* __restrict__ Kb,
                 const ushort* __restrict__ Vb,
                 const int* __restrict__ pidx, const int* __restrict__ pimask,
                 const float* __restrict__ u_prev, ushort* __restrict__ OA)
{
    const int tid  = threadIdx.x;
    const int lane = tid & 63, w = tid >> 6;
    const int kj = lane >> 3;
    const int c  = lane & 7;

    float lams[4];
#pragma unroll
    for (int i = 0; i < 4; ++i) lams[i] = 10.0f * __expf(-5.0f * u_prev[i]);
    int sl[4], ns = 0;
#pragma unroll
    for (int i = 0; i < 4; ++i) if (lams[i] >= 1.0f) sl[ns++] = i;

    const int id = blockIdx.x;                    // grid 4096
    if (id >= ns * 1024) return;

    int xcd = id & 7, j = id >> 3;
    int nh2 = 2 * ns;
    int hi = j % nh2, qt = j / nh2;
    int gh = hi * 8 + xcd;
    const int b = sl[gh >> 4], h = gh & 15;
    const int s0 = qt * 16 + w * 4;

    const size_t bh = (size_t)b * NH + h;
    const ushort* Qh = Qb + bh * NS * NDH;
    const ushort* Kh = Kb + bh * NS * NDH;
    const ushort* Vh = Vb + bh * NS * NDH;

    for (int r = 0; r < 4; ++r) {
        const int s = s0 + r;

        float qf[8];
        {
            union { bf16x8 v; ushort u[8]; } qv;
            qv.v = *(const bf16x8*)&Qh[(size_t)s * NDH + c * 8];
#pragma unroll
            for (int e = 0; e < 8; ++e) qf[e] = bf2f(qv.u[e]);
        }

        int kv[4], mv[4];
#pragma unroll
        for (int jj = 0; jj < 4; ++jj) {
            kv[jj] = pidx  [(size_t)s * NKSP + jj*8 + kj];
            mv[jj] = pimask[(size_t)s * NKSP + jj*8 + kj];
        }

        float sc[4];
#pragma unroll
        for (int jj = 0; jj < 4; ++jj) {
            union { bf16x8 v; ushort u[8]; } kc8;
            kc8.v = *(const bf16x8*)&Kh[(size_t)kv[jj] * NDH + c * 8];
            float d = 0.f;
#pragma unroll
            for (int e = 0; e < 8; ++e) d = fmaf(qf[e], bf2f(kc8.u[e]), d);
            d += __shfl_xor(d, 1);
            d += __shfl_xor(d, 2);
            d += __shfl_xor(d, 4);
            sc[jj] = mv[jj] ? d * SCALE : -INFINITY;
        }

        float mt = fmaxf(fmaxf(sc[0], sc[1]), fmaxf(sc[2], sc[3]));
        mt = fmaxf(mt, __shfl_xor(mt, 8));
        mt = fmaxf(mt, __shfl_xor(mt, 16));
        mt = fmaxf(mt, __shfl_xor(mt, 32));

        float p[4], psum = 0.f;
#pragma unroll
        for (int jj = 0; jj < 4; ++jj) {
            p[jj] = __expf(sc[jj] - mt);
            psum += p[jj];
        }
        psum += __shfl_xor(psum, 8);
        psum += __shfl_xor(psum, 16);
        psum += __shfl_xor(psum, 32);

        float o[8];
#pragma unroll
        for (int e = 0; e < 8; ++e) o[e] = 0.f;
#pragma unroll
        for (int jj = 0; jj < 4; ++jj) {
            union { bf16x8 v; ushort u[8]; } vc8;
            vc8.v = *(const bf16x8*)&Vh[(size_t)kv[jj] * NDH + c * 8];
#pragma unroll
            for (int e = 0; e < 8; ++e)
                o[e] = fmaf(p[jj], bf2f(vc8.u[e]), o[e]);
        }
#pragma unroll
        for (int e = 0; e < 8; ++e) {
            o[e] += __shfl_xor(o[e], 8);
            o[e] += __shfl_xor(o[e], 16);
            o[e] += __shfl_xor(o[e], 32);
        }

        if (kj == 0) {
            float inv = 1.f / psum;
            union { bf16x8 v; ushort u[8]; } ov;
#pragma unroll
            for (int e = 0; e < 8; ++e) ov.u[e] = f2bf(o[e] * inv);
            *(bf16x8*)&OA[((size_t)b*NS + s)*ND + h*NDH + c*8] = ov.v;
        }
    }
}

// ---------------------------------------------------------------------------
extern "C" void kernel_launch(void* const* d_in, const int* in_sizes, int n_in,
                              void* d_out, int out_size, void* d_ws, size_t ws_size,
                              hipStream_t stream)
{
    const float* x      = (const float*)d_in[0];
    const int*   pmask  = (const int*)  d_in[1];
    const int*   pidx   = (const int*)  d_in[2];
    const int*   pimask = (const int*)  d_in[3];
    const float* u_prev = (const float*)d_in[4];
    const float* Wq     = (const float*)d_in[5];
    const float* bq     = (const float*)d_in[6];
    const float* Wk     = (const float*)d_in[7];
    const float* bk     = (const float*)d_in[8];
    const float* Wv     = (const float*)d_in[9];
    const float* bv     = (const float*)d_in[10];
    const float* Wo     = (const float*)d_in[11];
    const float* bo     = (const float*)d_in[12];
    float* out = (float*)d_out;

    const size_t QSZ = (size_t)NB * NH * NS * NDH;   // 4,194,304 elements
    const size_t WSZ = (size_t)ND * ND;              // 1,048,576 elements
    ushort* xb  = (ushort*)d_ws;        // bf16 x              (8 MB)
    ushort* Qw  = xb  + QSZ;            // bf16 Q (b,h,s,dh)   (8 MB)
    ushort* Kw  = Qw  + QSZ;            // bf16 K              (8 MB)
    ushort* Vw  = Kw  + QSZ;            // bf16 V              (8 MB)
    ushort* Vtw = Vw  + QSZ;            // bf16 V^T (b,h,dh,s) (8 MB)
    ushort* Awb = Vtw + QSZ;            // bf16 attn out       (8 MB)
    ushort* Wqb = Awb + QSZ;            // bf16 weights (2 MB each)
    ushort* Wkb = Wqb + WSZ;
    ushort* Wvb = Wkb + WSZ;
    ushort* Wob = Wvb + WSZ;
    u64*    bmw = (u64*)(Wob + WSZ);    // packed mask (128 KB)

    f2bf_multi<<<dim3(4096, 6), 256, 0, stream>>>(
        x, Wq, Wk, Wv, Wo, pmask, xb, Wqb, Wkb, Wvb, Wob, bmw);

    gemm_qkv<<<dim3(24, 32), 256, 0, stream>>>(
        xb, Wqb, Wkb, Wvb, bq, bk, bv, Qw, Kw, Vw);

    transpose_v<<<1024, 256, 0, stream>>>(Vw, Vtw);

    attn_dense<<<2048, 256, 0, stream>>>(
        Qw, Kw, Vtw, bmw, u_prev, Awb);

    attn_sparse<<<4096, 256, 0, stream>>>(
        Qw, Kw, Vw, pidx, pimask, u_prev, Awb);

    gemm_out<<<dim3(ND/128, (NB*NS)/64), 256, 0, stream>>>(Awb, Wob, bo, out);
}

// Round 16
// 196.727 us; speedup vs baseline: 1.1252x; 1.0271x over previous
//
#include <hip/hip_runtime.h>
#include <hip/hip_bf16.h>
#include <cmath>

#define NB 4
#define NS 1024
#define ND 1024
#define NH 16
#define NDH 64
#define NKSP 32
#define SCALE 0.125f      // 1/sqrt(64)
#define LOG2E 1.44269504f
#define SCALE2 (SCALE * LOG2E)

typedef __attribute__((ext_vector_type(8))) short bf16x8;
typedef __attribute__((ext_vector_type(4))) float f32x4;
typedef unsigned long long u64;

#define AS1 __attribute__((address_space(1)))
#define AS3 __attribute__((address_space(3)))

__device__ __forceinline__ void gl_lds16(const void* g, void* l) {
    __builtin_amdgcn_global_load_lds((const AS1 void*)g, (AS3 void*)l, 16, 0, 0);
}

__device__ __forceinline__ ushort f2bf(float f) {
    union { __hip_bfloat16 h; ushort u; } cv;
    cv.h = __float2bfloat16(f);
    return cv.u;
}
__device__ __forceinline__ float bf2f(ushort u) {
    union { unsigned int i; float f; } cv;
    cv.i = ((unsigned int)u) << 16;
    return cv.f;
}
__device__ __forceinline__ float fexp2(float x) {
    return __builtin_amdgcn_exp2f(x);   // v_exp_f32 (base-2)
}

// ---------------------------------------------------------------------------
// y=0: x->bf16 (4096 blocks); y=1..4: W->bf16 (1024 blocks);
// y=5: pack pmask into bitwords (4096 blocks, one wave per u64 word).
// ---------------------------------------------------------------------------
__global__ __launch_bounds__(256)
void f2bf_multi(const float* __restrict__ x,
                const float* __restrict__ w0, const float* __restrict__ w1,
                const float* __restrict__ w2, const float* __restrict__ w3,
                const int* __restrict__ pm,
                ushort* __restrict__ xo,
                ushort* __restrict__ o0, ushort* __restrict__ o1,
                ushort* __restrict__ o2, ushort* __restrict__ o3,
                u64* __restrict__ bm)
{
    int y = blockIdx.y;
    if (y == 5) {
        int word = blockIdx.x * 4 + (threadIdx.x >> 6);
        int lane = threadIdx.x & 63;
        int row  = word >> 4, wcol = word & 15;
        int v = pm[(size_t)row * NS + wcol * 64 + lane];
        u64 b = __ballot(v != 0);
        if (lane == 0) bm[word] = b;
        return;
    }
    const float* src; ushort* dst; int nblk;
    if (y == 0)      { src = x;  dst = xo; nblk = 4096; }
    else if (y == 1) { src = w0; dst = o0; nblk = 1024; }
    else if (y == 2) { src = w1; dst = o1; nblk = 1024; }
    else if (y == 3) { src = w2; dst = o2; nblk = 1024; }
    else             { src = w3; dst = o3; nblk = 1024; }
    if (blockIdx.x >= (unsigned)nblk) return;
    int i = (blockIdx.x * 256 + threadIdx.x) * 4;
    float4 v = *(const float4*)&src[i];
    ushort4 o;
    o.x = f2bf(v.x); o.y = f2bf(v.y); o.z = f2bf(v.z); o.w = f2bf(v.w);
    *(ushort4*)&dst[i] = o;
}

// ---------------------------------------------------------------------------
// Fused QKV GEMM. grid (24,32): blockIdx.x: [0,8)=Q [8,16)=K [16,24)=V.
// r15 proven: BK=64 (16 barrier pairs), row-XOR both-sides swizzle
// (rule #21): LDS chunk (row,sub) holds global chunk (row, sub^(row&7));
// fragment read ck = (kk*4+quad) ^ (l16&7). LDS 32KB.
// ---------------------------------------------------------------------------
__global__ __launch_bounds__(256)
void gemm_qkv(const ushort* __restrict__ xb,
              const ushort* __restrict__ Wqb, const ushort* __restrict__ Wkb,
              const ushort* __restrict__ Wvb,
              const float* __restrict__ bq, const float* __restrict__ bk,
              const float* __restrict__ bv,
              ushort* __restrict__ Qo, ushort* __restrict__ Ko,
              ushort* __restrict__ Vo)
{
    constexpr int K = ND;
    __shared__ __attribute__((aligned(16))) ushort As[128 * 64];
    __shared__ __attribute__((aligned(16))) ushort Bs[128 * 64];

    const int tid  = threadIdx.x;
    const int lane = tid & 63, w = tid >> 6;
    const int wm = w >> 1, wn = w & 1;
    const int which = blockIdx.x >> 3;
    const int n0 = (blockIdx.x & 7) * 128;
    const int m0 = blockIdx.y * 128;
    const int quad = lane >> 4, l16 = lane & 15;

    const ushort* W = (which == 0) ? Wqb : (which == 1) ? Wkb : Wvb;
    const float* bias = (which == 0) ? bq : (which == 1) ? bk : bv;
    ushort* Out = (which == 0) ? Qo : (which == 1) ? Ko : Vo;

    f32x4 acc[4][4] = {};

    for (int k0 = 0; k0 < K; k0 += 64) {
        __syncthreads();
        // stage 128x64 A and B tiles (1024 chunks each; wave w: 256/tile)
#pragma unroll
        for (int u = 0; u < 4; ++u) {
            int cb = w * 256 + u * 64;
            int c  = cb + lane;
            int row = c >> 3, sub = c & 7;
            int kc = (sub ^ (row & 7)) * 8;       // source swizzle
            gl_lds16(xb + (size_t)(m0 + row) * K + k0 + kc, &As[cb * 8]);
            gl_lds16(W  + (size_t)(n0 + row) * K + k0 + kc, &Bs[cb * 8]);
        }
        __syncthreads();

        bf16x8 af[4][2], bfr[4][2];
#pragma unroll
        for (int mt = 0; mt < 4; ++mt) {
            int row = wm*64 + mt*16 + l16;        // row&7 == l16&7
#pragma unroll
            for (int kk = 0; kk < 2; ++kk) {
                int ck = (kk*4 + quad) ^ (l16 & 7);
                af[mt][kk] = *(const bf16x8*)&As[row*64 + ck*8];
            }
        }
#pragma unroll
        for (int nt = 0; nt < 4; ++nt) {
            int row = wn*64 + nt*16 + l16;
#pragma unroll
            for (int kk = 0; kk < 2; ++kk) {
                int ck = (kk*4 + quad) ^ (l16 & 7);
                bfr[nt][kk] = *(const bf16x8*)&Bs[row*64 + ck*8];
            }
        }
#pragma unroll
        for (int mt = 0; mt < 4; ++mt)
#pragma unroll
            for (int nt = 0; nt < 4; ++nt)
#pragma unroll
                for (int kk = 0; kk < 2; ++kk)
                    acc[mt][nt] = __builtin_amdgcn_mfma_f32_16x16x32_bf16(
                        af[mt][kk], bfr[nt][kk], acc[mt][nt], 0, 0, 0);
    }

#pragma unroll
    for (int nt = 0; nt < 4; ++nt) {
        int n = n0 + wn*64 + nt*16 + l16;
        float bz = bias[n];
        int hh = n >> 6, dh = n & 63;
#pragma unroll
        for (int mt = 0; mt < 4; ++mt) {
#pragma unroll
            for (int rg = 0; rg < 4; ++rg) {
                int m = m0 + wm*64 + mt*16 + quad*4 + rg;
                int b = m >> 10, s = m & (NS - 1);
                Out[(((size_t)(b*NH + hh))*NS + s)*NDH + dh] =
                    f2bf(acc[mt][nt][rg] + bz);
            }
        }
    }
}

// ---------------------------------------------------------------------------
// V transpose: [b,h,s,dh] -> [b,h,dh,s], 64x64 tiles, XOR-swizzled LDS,
// coalesced 16B global on both sides. 1024 blocks x 256 thr, 8KB LDS.
// (r12 exact — r14 proved folding this into gemm_qkv regresses.)
// ---------------------------------------------------------------------------
__global__ __launch_bounds__(256)
void transpose_v(const ushort* __restrict__ V, ushort* __restrict__ Vt)
{
    __shared__ __attribute__((aligned(16))) ushort T[64 * 64];

    const int t  = threadIdx.x;
    const int bh = blockIdx.x >> 4;               // 0..63 (b*16+h)
    const int st = blockIdx.x & 15;               // s-tile
    const ushort* Vh  = V  + (size_t)bh * NS * NDH + (size_t)st * 64 * NDH;
    ushort*       Vth = Vt + (size_t)bh * NDH * NS + st * 64;

#pragma unroll
    for (int i = 0; i < 2; ++i) {
        int g = i * 256 + t;                      // 0..511
        int srow = g >> 3, sub = g & 7;
        union { bf16x8 v; ushort u[8]; } x;
        x.v = *(const bf16x8*)&Vh[(size_t)srow * NDH + sub * 8];
#pragma unroll
        for (int e = 0; e < 8; ++e) {
            int dh = sub * 8 + e;                 // dh>>3 == sub
            T[dh*64 + (((srow >> 3) ^ sub) * 8) + (srow & 7)] = x.u[e];
        }
    }
    __syncthreads();
#pragma unroll
    for (int i = 0; i < 2; ++i) {
        int g = i * 256 + t;
        int dh = g >> 3, sc = g & 7;
        bf16x8 v = *(const bf16x8*)&T[dh*64 + ((sc ^ (dh >> 3)) * 8)];
        *(bf16x8*)&Vth[(size_t)dh * NS + sc * 8] = v;
    }
}

// ---------------------------------------------------------------------------
// Output GEMM: 64x128 tile -> 512 blocks.
// r16: BK 32 -> 64 (the ONLY change vs r15) — same mechanism as r15's
// gemm_qkv win: halves barrier/vmcnt-drain count (32 -> 16 steps), 16
// MFMAs per barrier pair (was 8). Same row-XOR both-sides swizzle.
// LDS = As 64x64 (8KB) + Bs 128x64 (16KB) = 24KB -> >=4 blocks/CU.
// ---------------------------------------------------------------------------
__global__ __launch_bounds__(256)
void gemm_out(const ushort* __restrict__ A, const ushort* __restrict__ W,
              const float* __restrict__ bias, float* __restrict__ Cout)
{
    constexpr int K = ND;
    __shared__ __attribute__((aligned(16))) ushort As[64 * 64];
    __shared__ __attribute__((aligned(16))) ushort Bs[128 * 64];

    const int tid  = threadIdx.x;
    const int lane = tid & 63, w = tid >> 6;
    const int wm = w & 1, wn = w >> 1;
    const int m0 = blockIdx.y * 64, n0 = blockIdx.x * 128;
    const int quad = lane >> 4, l16 = lane & 15;

    f32x4 acc[2][4] = {};

    for (int k0 = 0; k0 < K; k0 += 64) {
        __syncthreads();
        // stage A: 64x64 tile = 512 chunks (2/thread)
#pragma unroll
        for (int u = 0; u < 2; ++u) {
            int cb = w * 128 + u * 64;
            int c  = cb + lane;
            int row = c >> 3, sub = c & 7;
            int kc = (sub ^ (row & 7)) * 8;       // source swizzle
            gl_lds16(A + (size_t)(m0 + row) * K + k0 + kc, &As[cb * 8]);
        }
        // stage B: 128x64 tile = 1024 chunks (4/thread)
#pragma unroll
        for (int u = 0; u < 4; ++u) {
            int cb = w * 256 + u * 64;
            int c  = cb + lane;
            int row = c >> 3, sub = c & 7;
            int kc = (sub ^ (row & 7)) * 8;
            gl_lds16(W + (size_t)(n0 + row) * K + k0 + kc, &Bs[cb * 8]);
        }
        __syncthreads();

        bf16x8 af[2][2], bfr[4][2];
#pragma unroll
        for (int mt = 0; mt < 2; ++mt) {
            int row = wm*32 + mt*16 + l16;        // row&7 == l16&7
#pragma unroll
            for (int kk = 0; kk < 2; ++kk) {
                int ck = (kk*4 + quad) ^ (l16 & 7);
                af[mt][kk] = *(const bf16x8*)&As[row*64 + ck*8];
            }
        }
#pragma unroll
        for (int nt = 0; nt < 4; ++nt) {
            int row = wn*64 + nt*16 + l16;
#pragma unroll
            for (int kk = 0; kk < 2; ++kk) {
                int ck = (kk*4 + quad) ^ (l16 & 7);
                bfr[nt][kk] = *(const bf16x8*)&Bs[row*64 + ck*8];
            }
        }
#pragma unroll
        for (int mt = 0; mt < 2; ++mt)
#pragma unroll
            for (int nt = 0; nt < 4; ++nt)
#pragma unroll
                for (int kk = 0; kk < 2; ++kk)
                    acc[mt][nt] = __builtin_amdgcn_mfma_f32_16x16x32_bf16(
                        af[mt][kk], bfr[nt][kk], acc[mt][nt], 0, 0, 0);
    }

#pragma unroll
    for (int nt = 0; nt < 4; ++nt) {
        int n = n0 + wn*64 + nt*16 + l16;
        float bz = bias[n];
#pragma unroll
        for (int mt = 0; mt < 2; ++mt) {
#pragma unroll
            for (int rg = 0; rg < 4; ++rg) {
                int m = m0 + wm*32 + mt*16 + quad*4 + rg;
                Cout[(size_t)m * ND + n] = acc[mt][nt][rg] + bz;
            }
        }
    }
}

// ---------------------------------------------------------------------------
// attn_dense (r12 exact): 32 q-rows/block, 4 waves = 4-way kt split,
// LDS-K staging + global-V, bm from L2, additive partials + LDS combine.
// ---------------------------------------------------------------------------
#define DSTAGE(T4)                                                            \
    _Pragma("unroll")                                                         \
    for (int u = 0; u < 8; ++u) {                                             \
        int cb = w * 512 + u * 64;                                            \
        int c  = cb + lane;                                                   \
        int tk = c >> 9, c2 = c & 511;                                        \
        int row = c2 >> 3, sub = c2 & 7;                                      \
        const ushort* src = Kh + (((size_t)(((T4)*4 + tk)*64 + row)) << 6)    \
                               + ((sub ^ (row & 7)) << 3);                    \
        gl_lds16(src, KK + (size_t)cb * 8);                                   \
    }

#define DLOADKV(KF, VF, KT)                                                   \
    _Pragma("unroll")                                                         \
    for (int nt = 0; nt < 4; ++nt)                                            \
        _Pragma("unroll")                                                     \
        for (int kk = 0; kk < 2; ++kk) {                                      \
            int rowk = nt*16 + l16;                                           \
            int ck = (kk*4 + quad) ^ (l16 & 7);                               \
            KF[nt][kk] = *(const bf16x8*)&KK[w*4096 + rowk*64 + ck*8];        \
            VF[nt][kk] = *(const bf16x8*)                                     \
                &Vth[(size_t)(nt*16 + l16) * NS + (KT)*64 + kk*32 + quad*8];  \
        }

#define DSTEP(KF, VF, M0, M1)                                                 \
    _Pragma("unroll")                                                         \
    for (int qh = 0; qh < 2; ++qh) {                                          \
        const int qrow = qh*16 + l16;                                         \
        u64 wqm = ((qh == 0) ? (M0) : (M1)) >> (quad * 4);                    \
        f32x4 s_acc[4] = {};                                                  \
        __builtin_amdgcn_s_setprio(1);                                        \
        _Pragma("unroll")                                                     \
        for (int nt = 0; nt < 4; ++nt)                                        \
            _Pragma("unroll")                                                 \
            for (int kk = 0; kk < 2; ++kk)                                    \
                s_acc[nt] = __builtin_amdgcn_mfma_f32_16x16x32_bf16(          \
                    KF[nt][kk], qf[qh][kk], s_acc[nt], 0, 0, 0);              \
        __builtin_amdgcn_s_setprio(0);                                        \
        _Pragma("unroll")                                                     \
        for (int nt = 0; nt < 4; ++nt) {                                      \
            ushort4 pk;                                                       \
            float p0 = fexp2(fmaf(s_acc[nt][0], SCALE2,                       \
                 ((wqm >> (nt*16 + 0)) & 1ULL) ? 0.f : nlam2));               \
            float p1 = fexp2(fmaf(s_acc[nt][1], SCALE2,                       \
                 ((wqm >> (nt*16 + 1)) & 1ULL) ? 0.f : nlam2));               \
            float p2 = fexp2(fmaf(s_acc[nt][2], SCALE2,                       \
                 ((wqm >> (nt*16 + 2)) & 1ULL) ? 0.f : nlam2));               \
            float p3 = fexp2(fmaf(s_acc[nt][3], SCALE2,                       \
                 ((wqm >> (nt*16 + 3)) & 1ULL) ? 0.f : nlam2));               \
            pk.x = f2bf(p0); pk.y = f2bf(p1);                                 \
            pk.z = f2bf(p2); pk.w = f2bf(p3);                                 \
            *(ushort4*)&Ps[w*2304 + qrow*72 + nt*16 + quad*4] = pk;           \
        }                                                                     \
        bf16x8 pf[2];                                                         \
        _Pragma("unroll")                                                     \
        for (int kk = 0; kk < 2; ++kk)                                        \
            pf[kk] = *(const bf16x8*)&Ps[w*2304 + qrow*72 + kk*32 + quad*8];  \
        __builtin_amdgcn_s_setprio(1);                                        \
        _Pragma("unroll")                                                     \
        for (int kk = 0; kk < 2; ++kk) {                                      \
            l_acc[qh] = __builtin_amdgcn_mfma_f32_16x16x32_bf16(              \
                pf[kk], ones.v, l_acc[qh], 0, 0, 0);                          \
            _Pragma("unroll")                                                 \
            for (int nt = 0; nt < 4; ++nt)                                    \
                o_acc[qh][nt] = __builtin_amdgcn_mfma_f32_16x16x32_bf16(      \
                    pf[kk], VF[nt][kk], o_acc[qh][nt], 0, 0, 0);              \
        }                                                                     \
        __builtin_amdgcn_s_setprio(0);                                        \
    }

__global__ __launch_bounds__(256)
void attn_dense(const ushort* __restrict__ Qb, const ushort* __restrict__ Kb,
                const ushort* __restrict__ Vt, const u64* __restrict__ bm,
                const float* __restrict__ u_prev, ushort* __restrict__ OA)
{
    __shared__ __attribute__((aligned(16))) ushort SM[25600];
    ushort* KK = SM;
    ushort* Ps = SM + 16384;

    const int tid  = threadIdx.x;
    const int lane = tid & 63, w = tid >> 6;
    const int quad = lane >> 4, l16 = lane & 15;

    float lams[4];
#pragma unroll
    for (int i = 0; i < 4; ++i) lams[i] = 10.0f * __expf(-5.0f * u_prev[i]);
    int dl[4], nd = 0;
#pragma unroll
    for (int i = 0; i < 4; ++i) if (lams[i] < 1.0f) dl[nd++] = i;

    const int id = blockIdx.x;                    // grid 2048
    if (id >= nd * 512) return;

    int xcd = id & 7, j = id >> 3;
    int nh2 = 2 * nd;
    int hi = j % nh2, qt = j / nh2;
    int gh = hi * 8 + xcd;
    const int b = dl[gh >> 4], h = gh & 15;
    const int s0 = qt * 32;
    const float nlam2 = -lams[b] * LOG2E;

    const size_t bh = (size_t)b * NH + h;
    const ushort* Qh  = Qb + bh * NS * NDH;
    const ushort* Kh  = Kb + bh * NS * NDH;
    const ushort* Vth = Vt + bh * NDH * NS;

    bf16x8 qf[2][2];
#pragma unroll
    for (int qh = 0; qh < 2; ++qh)
#pragma unroll
        for (int kk = 0; kk < 2; ++kk)
            qf[qh][kk] = *(const bf16x8*)
                &Qh[(size_t)(s0 + qh*16 + l16) * NDH + kk*32 + quad*8];

    union { bf16x8 v; ushort s[8]; } ones;
#pragma unroll
    for (int i = 0; i < 8; ++i) ones.s[i] = 0x3F80;

    f32x4 o_acc[2][4] = {};
    f32x4 l_acc[2] = {};

    for (int t = 0; t < 4; ++t) {
        if (t) __syncthreads();
        DSTAGE(t);
        const int kt = 4 * t + w;
        u64 m0 = bm[(size_t)(s0 +  0 + l16) * 16 + kt];
        u64 m1 = bm[(size_t)(s0 + 16 + l16) * 16 + kt];
        __syncthreads();
        bf16x8 kf[4][2], vf[4][2];
        DLOADKV(kf, vf, kt);
        DSTEP(kf, vf, m0, m1);
    }
    __syncthreads();

    float* POUT = (float*)SM;
    if (w != 0) {
        int base = (w - 1) * 2560;
#pragma unroll
        for (int qh = 0; qh < 2; ++qh) {
#pragma unroll
            for (int nt = 0; nt < 4; ++nt)
#pragma unroll
                for (int rg = 0; rg < 4; ++rg)
                    POUT[base + (qh*16 + nt*4 + rg)*64 + lane] =
                        o_acc[qh][nt][rg];
#pragma unroll
            for (int rg = 0; rg < 4; ++rg)
                POUT[base + (32 + qh*4 + rg)*64 + lane] = l_acc[qh][rg];
        }
    }
    __syncthreads();
    if (w == 0) {
#pragma unroll
        for (int s = 0; s < 3; ++s) {
            int base = s * 2560;
#pragma unroll
            for (int qh = 0; qh < 2; ++qh) {
#pragma unroll
                for (int nt = 0; nt < 4; ++nt)
#pragma unroll
                    for (int rg = 0; rg < 4; ++rg)
                        o_acc[qh][nt][rg] +=
                            POUT[base + (qh*16 + nt*4 + rg)*64 + lane];
#pragma unroll
                for (int rg = 0; rg < 4; ++rg)
                    l_acc[qh][rg] += POUT[base + (32 + qh*4 + rg)*64 + lane];
            }
        }
#pragma unroll
        for (int qh = 0; qh < 2; ++qh) {
            float inv[4];
#pragma unroll
            for (int rg = 0; rg < 4; ++rg) inv[rg] = 1.f / l_acc[qh][rg];
#pragma unroll
            for (int nt = 0; nt < 4; ++nt)
#pragma unroll
                for (int rg = 0; rg < 4; ++rg) {
                    int m = qh*16 + quad*4 + rg;
                    OA[((size_t)b*NS + s0 + m)*ND + h*NDH + nt*16 + l16] =
                        f2bf(o_acc[qh][nt][rg] * inv[rg]);
                }
        }
    }
}

// ---------------------------------------------------------------------------
// attn_sparse (r12 exact): coalesced gather, wave = (kj8 x c8), no LDS.
// ---------------------------------------------------------------------------
__global__ __launch_bounds__(256)
void attn_sparse(const ushort* __restrict__ Qb, const ushort* __restrict__ Kb,
                 const ushort* __restrict__ Vb,
                 const int* __restrict__ pidx, const int* __restrict__ pimask,
                 const float* __restrict__ u_prev, ushort* __restrict__ OA)
{
    const int tid  = threadIdx.x;
    const int lane = tid & 63, w = tid >> 6;
    const int kj = lane >> 3;
    const int c  = lane & 7;

    float lams[4];
#pragma unroll
    for (int i = 0; i < 4; ++i) lams[i] = 10.0f * __expf(-5.0f * u_prev[i]);
    int sl[4], ns = 0;
#pragma unroll
    for (int i = 0; i < 4; ++i) if (lams[i] >= 1.0f) sl[ns++] = i;

    const int id = blockIdx.x;                    // grid 4096
    if (id >= ns * 1024) return;

    int xcd = id & 7, j = id >> 3;
    int nh2 = 2 * ns;
    int hi = j % nh2, qt = j / nh2;
    int gh = hi * 8 + xcd;
    const int b = sl[gh >> 4], h = gh & 15;
    const int s0 = qt * 16 + w * 4;

    const size_t bh = (size_t)b * NH + h;
    const ushort* Qh = Qb + bh * NS * NDH;
    const ushort* Kh = Kb + bh * NS * NDH;
    const ushort* Vh = Vb + bh * NS * NDH;

    for (int r = 0; r < 4; ++r) {
        const int s = s0 + r;

        float qf[8];
        {
            union { bf16x8 v; ushort u[8]; } qv;
            qv.v = *(const bf16x8*)&Qh[(size_t)s * NDH + c * 8];
#pragma unroll
            for (int e = 0; e < 8; ++e) qf[e] = bf2f(qv.u[e]);
        }

        int kv[4], mv[4];
#pragma unroll
        for (int jj = 0; jj < 4; ++jj) {
            kv[jj] = pidx  [(size_t)s * NKSP + jj*8 + kj];
            mv[jj] = pimask[(size_t)s * NKSP + jj*8 + kj];
        }

        float sc[4];
#pragma unroll
        for (int jj = 0; jj < 4; ++jj) {
            union { bf16x8 v; ushort u[8]; } kc8;
            kc8.v = *(const bf16x8*)&Kh[(size_t)kv[jj] * NDH + c * 8];
            float d = 0.f;
#pragma unroll
            for (int e = 0; e < 8; ++e) d = fmaf(qf[e], bf2f(kc8.u[e]), d);
            d += __shfl_xor(d, 1);
            d += __shfl_xor(d, 2);
            d += __shfl_xor(d, 4);
            sc[jj] = mv[jj] ? d * SCALE : -INFINITY;
        }

        float mt = fmaxf(fmaxf(sc[0], sc[1]), fmaxf(sc[2], sc[3]));
        mt = fmaxf(mt, __shfl_xor(mt, 8));
        mt = fmaxf(mt, __shfl_xor(mt, 16));
        mt = fmaxf(mt, __shfl_xor(mt, 32));

        float p[4], psum = 0.f;
#pragma unroll
        for (int jj = 0; jj < 4; ++jj) {
            p[jj] = __expf(sc[jj] - mt);
            psum += p[jj];
        }
        psum += __shfl_xor(psum, 8);
        psum += __shfl_xor(psum, 16);
        psum += __shfl_xor(psum, 32);

        float o[8];
#pragma unroll
        for (int e = 0; e < 8; ++e) o[e] = 0.f;
#pragma unroll
        for (int jj = 0; jj < 4; ++jj) {
            union { bf16x8 v; ushort u[8]; } vc8;
            vc8.v = *(const bf16x8*)&Vh[(size_t)kv[jj] * NDH + c * 8];
#pragma unroll
            for (int e = 0; e < 8; ++e)
                o[e] = fmaf(p[jj], bf2f(vc8.u[e]), o[e]);
        }
#pragma unroll
        for (int e = 0; e < 8; ++e) {
            o[e] += __shfl_xor(o[e], 8);
            o[e] += __shfl_xor(o[e], 16);
            o[e] += __shfl_xor(o[e], 32);
        }

        if (kj == 0) {
            float inv = 1.f / psum;
            union { bf16x8 v; ushort u[8]; } ov;
#pragma unroll
            for (int e = 0; e < 8; ++e) ov.u[e] = f2bf(o[e] * inv);
            *(bf16x8*)&OA[((size_t)b*NS + s)*ND + h*NDH + c*8] = ov.v;
        }
    }
}

// ---------------------------------------------------------------------------
extern "C" void kernel_launch(void* const* d_in, const int* in_sizes, int n_in,
                              void* d_out, int out_size, void* d_ws, size_t ws_size,
                              hipStream_t stream)
{
    const float* x      = (const float*)d_in[0];
    const int*   pmask  = (const int*)  d_in[1];
    const int*   pidx   = (const int*)  d_in[2];
    const int*   pimask = (const int*)  d_in[3];
    const float* u_prev = (const float*)d_in[4];
    const float* Wq     = (const float*)d_in[5];
    const float* bq     = (const float*)d_in[6];
    const float* Wk     = (const float*)d_in[7];
    const float* bk     = (const float*)d_in[8];
    const float* Wv     = (const float*)d_in[9];
    const float* bv     = (const float*)d_in[10];
    const float* Wo     = (const float*)d_in[11];
    const float* bo     = (const float*)d_in[12];
    float* out = (float*)d_out;

    const size_t QSZ = (size_t)NB * NH * NS * NDH;   // 4,194,304 elements
    const size_t WSZ = (size_t)ND * ND;              // 1,048,576 elements
    ushort* xb  = (ushort*)d_ws;        // bf16 x              (8 MB)
    ushort* Qw  = xb  + QSZ;            // bf16 Q (b,h,s,dh)   (8 MB)
    ushort* Kw  = Qw  + QSZ;            // bf16 K              (8 MB)
    ushort* Vw  = Kw  + QSZ;            // bf16 V              (8 MB)
    ushort* Vtw = Vw  + QSZ;            // bf16 V^T (b,h,dh,s) (8 MB)
    ushort* Awb = Vtw + QSZ;            // bf16 attn out       (8 MB)
    ushort* Wqb = Awb + QSZ;            // bf16 weights (2 MB each)
    ushort* Wkb = Wqb + WSZ;
    ushort* Wvb = Wkb + WSZ;
    ushort* Wob = Wvb + WSZ;
    u64*    bmw = (u64*)(Wob + WSZ);    // packed mask (128 KB)

    f2bf_multi<<<dim3(4096, 6), 256, 0, stream>>>(
        x, Wq, Wk, Wv, Wo, pmask, xb, Wqb, Wkb, Wvb, Wob, bmw);

    gemm_qkv<<<dim3(24, 32), 256, 0, stream>>>(
        xb, Wqb, Wkb, Wvb, bq, bk, bv, Qw, Kw, Vw);

    transpose_v<<<1024, 256, 0, stream>>>(Vw, Vtw);

    attn_dense<<<2048, 256, 0, stream>>>(
        Qw, Kw, Vtw, bmw, u_prev, Awb);

    attn_sparse<<<4096, 256, 0, stream>>>(
        Qw, Kw, Vw, pidx, pimask, u_prev, Awb);

    gemm_out<<<dim3(ND/128, (NB*NS)/64), 256, 0, stream>>>(Awb, Wob, bo, out);
}